// Round 2
// baseline (359.298 us; speedup 1.0000x reference)
//
#include <hip/hip_runtime.h>
#include <hip/hip_bf16.h>

// ---------------------------------------------------------------------------
// CrossAttention block: softmax(QK^T/sqrt(d)) V, out-proj, residual, LayerNorm
// B=2, N=2048, C=768, H=12, Dh=64.  All GEMM-shaped compute in bf16 MFMA
// (mfma_f32_16x16x32_bf16), fp32 accumulation, fp32 LayerNorm epilogue.
// R2: attention rewritten with swapped QK^T (lane-local softmax rows),
//     in-register P transpose (pack+shfl), register K/V prefetch, zero LDS.
// ---------------------------------------------------------------------------

typedef unsigned short ushort_t;
typedef __bf16 bf16x8 __attribute__((ext_vector_type(8)));
typedef float  f32x4  __attribute__((ext_vector_type(4)));
typedef unsigned int uint32x4 __attribute__((ext_vector_type(4)));

constexpr int C_DIM  = 768;
constexpr int HEADS  = 12;
constexpr int DH     = 64;
constexpr int BATCH  = 2;
constexpr int SEQ    = 2048;
constexpr int MTOT   = BATCH * SEQ;      // 4096 rows
constexpr float EPS  = 1e-5f;
constexpr float SCALE = 0.125f;          // Dh^-0.5 = 1/8 (folded into Q proj)

// workspace layout (bytes)
constexpr size_t SZ_X = (size_t)MTOT * C_DIM;   // 3,145,728 elements
constexpr size_t SZ_W = (size_t)C_DIM * C_DIM;  // 589,824 elements
constexpr size_t B_XQ  = 0;
constexpr size_t B_XK  = B_XQ  + SZ_X * 2;
constexpr size_t B_XV  = B_XK  + SZ_X * 2;
constexpr size_t B_WQT = B_XV  + SZ_X * 2;
constexpr size_t B_WKT = B_WQT + SZ_W * 2;
constexpr size_t B_WVT = B_WKT + SZ_W * 2;
constexpr size_t B_WOT = B_WVT + SZ_W * 2;
constexpr size_t B_QH  = B_WOT + SZ_W * 2;      // [B,H,N,DH] bf16 (pre-scaled)
constexpr size_t B_KH  = B_QH  + SZ_X * 2;      // [B,H,N,DH] bf16
constexpr size_t B_VT  = B_KH  + SZ_X * 2;      // [B,H,DH,N] bf16 (transposed!)
constexpr size_t B_O   = B_VT  + SZ_X * 2;      // [MTOT,C] bf16 attn output
constexpr size_t B_XR  = B_O   + SZ_X * 2;      // [MTOT,C] fp32 pre-LN

__device__ __forceinline__ ushort_t f2bf(float f) {
  __hip_bfloat16 h = __float2bfloat16(f);
  return __builtin_bit_cast(unsigned short, h);
}
__device__ __forceinline__ unsigned pack2bf(float a, float b) {
  return (unsigned)f2bf(a) | ((unsigned)f2bf(b) << 16);
}

// async global->LDS, 16B per lane.  LDS dest must be linear (base + lane*16).
__device__ __forceinline__ void gload_lds16(const void* g, void* l) {
  __builtin_amdgcn_global_load_lds(
      (const __attribute__((address_space(1))) unsigned int*)g,
      (__attribute__((address_space(3))) unsigned int*)l,
      16, 0, 0);
}

// ---------------------------------------------------------------------------
// 1) fp32 -> bf16 elementwise convert, all three activations in one launch
// ---------------------------------------------------------------------------
__global__ __launch_bounds__(256) void cvt3_kernel(
    const float* __restrict__ s0, const float* __restrict__ s1,
    const float* __restrict__ s2,
    ushort_t* __restrict__ d0, ushort_t* __restrict__ d1,
    ushort_t* __restrict__ d2, int n4) {
  const float* src = blockIdx.y == 0 ? s0 : blockIdx.y == 1 ? s1 : s2;
  ushort_t*    dst = blockIdx.y == 0 ? d0 : blockIdx.y == 1 ? d1 : d2;
  int i = blockIdx.x * 256 + threadIdx.x;
  if (i >= n4) return;
  float4 v = ((const float4*)src)[i];
  ushort4 o;
  o.x = f2bf(v.x); o.y = f2bf(v.y); o.z = f2bf(v.z); o.w = f2bf(v.w);
  ((ushort4*)dst)[i] = o;
}

// ---------------------------------------------------------------------------
// 2) transpose+convert the 4 weight matrices:  Wt[n][k] = W[k][n]  (bf16)
// ---------------------------------------------------------------------------
__global__ __launch_bounds__(256) void wtrans_kernel(
    const float* __restrict__ W0, const float* __restrict__ W1,
    const float* __restrict__ W2, const float* __restrict__ W3,
    ushort_t* T0, ushort_t* T1, ushort_t* T2, ushort_t* T3) {
  const float* W = blockIdx.z == 0 ? W0 : blockIdx.z == 1 ? W1 : blockIdx.z == 2 ? W2 : W3;
  ushort_t*    T = blockIdx.z == 0 ? T0 : blockIdx.z == 1 ? T1 : blockIdx.z == 2 ? T2 : T3;
  __shared__ float tile[32][33];   // +1 pad: conflict-free transpose
  int tx = threadIdx.x & 31, ty = threadIdx.x >> 5;   // 32 x 8
  int x0 = blockIdx.x * 32, y0 = blockIdx.y * 32;
#pragma unroll
  for (int i = 0; i < 32; i += 8)
    tile[ty + i][tx] = W[(size_t)(y0 + ty + i) * C_DIM + x0 + tx];
  __syncthreads();
#pragma unroll
  for (int i = 0; i < 32; i += 8)
    T[(size_t)(x0 + ty + i) * C_DIM + y0 + tx] = f2bf(tile[tx][ty + i]);
}

// ---------------------------------------------------------------------------
// GEMM mainloop: C[128x128] = A[128xK] * Bt[128xK]^T, K=768, BK=32.
// ---------------------------------------------------------------------------
__device__ __forceinline__ void gemm128_mainloop(
    const ushort_t* __restrict__ A, const ushort_t* __restrict__ Bt,
    int rowBase, int colBase, ushort_t* ldsA, ushort_t* ldsB, f32x4 acc[4][4]) {
  const int tid = threadIdx.x;
  const int wave = tid >> 6, lane = tid & 63;
  const int wr = wave >> 1, wc = wave & 1;
  const int lrow = lane & 15, lk = lane >> 4;
  const int sr = tid >> 2, sk = (tid & 3) * 8;   // staging: row tid/4, 8-elem seg
  const int K = C_DIM;

  const ushort_t* ga0 = A  + (size_t)(rowBase + sr)      * K + sk;
  const ushort_t* ga1 = A  + (size_t)(rowBase + 64 + sr) * K + sk;
  const ushort_t* gb0 = Bt + (size_t)(colBase + sr)      * K + sk;
  const ushort_t* gb1 = Bt + (size_t)(colBase + 64 + sr) * K + sk;
  ushort_t* la = ldsA + sr * 32 + sk;            // byte offset tid*16 (linear)
  ushort_t* lb = ldsB + sr * 32 + sk;

  for (int kt = 0; kt < K; kt += 32) {
    gload_lds16(ga0 + kt, la);
    gload_lds16(ga1 + kt, la + 64 * 32);
    gload_lds16(gb0 + kt, lb);
    gload_lds16(gb1 + kt, lb + 64 * 32);
    asm volatile("s_waitcnt vmcnt(0)" ::: "memory");
    __syncthreads();
    bf16x8 af[4], bfr[4];
#pragma unroll
    for (int m = 0; m < 4; m++)
      af[m] = *(const bf16x8*)(ldsA + (wr * 64 + m * 16 + lrow) * 32 + lk * 8);
#pragma unroll
    for (int n = 0; n < 4; n++)
      bfr[n] = *(const bf16x8*)(ldsB + (wc * 64 + n * 16 + lrow) * 32 + lk * 8);
#pragma unroll
    for (int m = 0; m < 4; m++)
#pragma unroll
      for (int n = 0; n < 4; n++)
        acc[m][n] = __builtin_amdgcn_mfma_f32_16x16x32_bf16(af[m], bfr[n], acc[m][n], 0, 0, 0);
    __syncthreads();
  }
}

// ---------------------------------------------------------------------------
// 3) fused QKV projection.  grid = (6 colTiles, 32 rowTiles, 3 matrices)
//    q (pre-scaled by Dh^-0.5), k -> [B,H,N,DH] bf16, v -> [B,H,DH,N] bf16
// ---------------------------------------------------------------------------
__global__ __launch_bounds__(256) void gemm_qkv_kernel(
    const ushort_t* __restrict__ Xq, const ushort_t* __restrict__ Xk,
    const ushort_t* __restrict__ Xv,
    const ushort_t* __restrict__ Wqt, const ushort_t* __restrict__ Wkt,
    const ushort_t* __restrict__ Wvt,
    const float* __restrict__ bq, const float* __restrict__ bk,
    const float* __restrict__ bv,
    ushort_t* Qh, ushort_t* Kh, ushort_t* Vt) {
  const int mat = blockIdx.z;
  const ushort_t* A  = mat == 0 ? Xq  : mat == 1 ? Xk  : Xv;
  const ushort_t* Bt = mat == 0 ? Wqt : mat == 1 ? Wkt : Wvt;
  const float* bias  = mat == 0 ? bq  : mat == 1 ? bk  : bv;

  __shared__ __align__(16) ushort_t ldsA[128 * 32];
  __shared__ __align__(16) ushort_t ldsB[128 * 32];

  const int rowBase = blockIdx.y * 128;
  const int colBase = blockIdx.x * 128;
  f32x4 acc[4][4];
#pragma unroll
  for (int m = 0; m < 4; m++)
#pragma unroll
    for (int n = 0; n < 4; n++)
#pragma unroll
      for (int r = 0; r < 4; r++) acc[m][n][r] = 0.f;

  gemm128_mainloop(A, Bt, rowBase, colBase, ldsA, ldsB, acc);

  const int lane = threadIdx.x & 63, wave = threadIdx.x >> 6;
  const int wr = wave >> 1, wc = wave & 1;
  const int lrow = lane & 15, lk = lane >> 4;
  const float sc = (mat == 0) ? SCALE : 1.0f;

  __hip_bfloat16* dqk = (__hip_bfloat16*)(mat == 0 ? Qh : Kh);
  __hip_bfloat16* dvt = (__hip_bfloat16*)Vt;
#pragma unroll
  for (int n = 0; n < 4; n++) {
    const int col = colBase + wc * 64 + n * 16 + lrow;
    const float bval = bias[col];
    const int hh = col >> 6, dd = col & 63;
#pragma unroll
    for (int m = 0; m < 4; m++) {
#pragma unroll
      for (int r = 0; r < 4; r++) {
        const int row = rowBase + wr * 64 + m * 16 + lk * 4 + r;
        const int bb = row >> 11, nn = row & 2047;
        const float val = (acc[m][n][r] + bval) * sc;
        if (mat < 2) {
          dqk[(((size_t)(bb * HEADS + hh) * SEQ + nn) << 6) + dd] = __float2bfloat16(val);
        } else {
          dvt[((size_t)(bb * HEADS + hh) * DH + dd) * SEQ + nn] = __float2bfloat16(val);
        }
      }
    }
  }
}

// ---------------------------------------------------------------------------
// 4) flash attention, swapped-QK^T form.  grid = (32 qTiles, 24 bh).
//    4 waves x 16 q-rows.  Each lane owns ONE q-row (col of S^T):
//      S^T = mfma(K_frag, Q_frag):  lane(lrow,lk) holds S[q=lrow][kv=n*16+lk*4+r]
//    -> softmax reduce = 15 reg ops + 2 shfl stages (xor16, xor32).
//    P -> PV B-operand via in-register pack(bf16) + 16 shfl + cndmask selects.
//    O^T accumulated (rows=d, col=q).  K prefetched one tile ahead; V issued
//    right after QK^T so its latency hides under softmax.  Zero LDS.
// ---------------------------------------------------------------------------
__global__ __launch_bounds__(256) void attn_kernel(
    const ushort_t* __restrict__ Qh, const ushort_t* __restrict__ Kh,
    const ushort_t* __restrict__ Vt, ushort_t* __restrict__ O) {
  const int qt = blockIdx.x;          // 0..31
  const int bh = blockIdx.y;          // 0..23
  const int b = bh / HEADS, h = bh % HEADS;
  const ushort_t* Qp = Qh + (size_t)bh * SEQ * DH;
  const ushort_t* Kp = Kh + (size_t)bh * SEQ * DH;
  const ushort_t* Vp = Vt + (size_t)bh * DH * SEQ;

  const int tid = threadIdx.x, wave = tid >> 6, lane = tid & 63;
  const int lrow = lane & 15, lk = lane >> 4;
  const int qrow0 = qt * 64 + wave * 16;

  // P-shuffle source lanes: src lk_s = (lk&1)*2 + {0,1}
  const int srcA = lrow + ((lane & 16) << 1);   // lrow + 32*(lk&1)
  const int srcB = srcA + 16;
  const bool hiN = (lane & 32) != 0;            // lk>>1: selects n-frag +1

  // Q B-frags (Q pre-scaled by 1/8)
  bf16x8 qf[2];
#pragma unroll
  for (int kk = 0; kk < 2; kk++)
    qf[kk] = *(const bf16x8*)&Qp[(size_t)(qrow0 + lrow) * DH + kk * 32 + lk * 8];

  // K A-frags for kv=0 (prologue)
  bf16x8 kf[4][2];
#pragma unroll
  for (int n = 0; n < 4; n++)
#pragma unroll
    for (int kk = 0; kk < 2; kk++)
      kf[n][kk] = *(const bf16x8*)&Kp[(size_t)(n * 16 + lrow) * DH + kk * 32 + lk * 8];

  f32x4 oacc[4];   // O^T frag t: rows d=t*16+lk*4+r, col q=lrow
#pragma unroll
  for (int t = 0; t < 4; t++)
#pragma unroll
    for (int r = 0; r < 4; r++) oacc[t][r] = 0.f;
  float mrun = -1e30f, lrun = 0.f;

#pragma unroll 1
  for (int kv = 0; kv < SEQ; kv += 64) {
    // ---- S^T = K Q^T : lane gets 16 P-values of its own q-row ----
    f32x4 st[4];
#pragma unroll
    for (int n = 0; n < 4; n++) {
#pragma unroll
      for (int r = 0; r < 4; r++) st[n][r] = 0.f;
#pragma unroll
      for (int kk = 0; kk < 2; kk++)
        st[n] = __builtin_amdgcn_mfma_f32_16x16x32_bf16(kf[n][kk], qf[kk], st[n], 0, 0, 0);
    }

    // ---- issue V loads now; consumed after softmax (latency hidden) ----
    bf16x8 vf[4][2];
#pragma unroll
    for (int t = 0; t < 4; t++)
#pragma unroll
      for (int c = 0; c < 2; c++)
        vf[t][c] = *(const bf16x8*)&Vp[(size_t)(t * 16 + lrow) * SEQ + kv + c * 32 + lk * 8];

    // ---- online softmax, lane-local row ----
    float tm = fmaxf(fmaxf(fmaxf(st[0][0], st[0][1]), fmaxf(st[0][2], st[0][3])),
                     fmaxf(fmaxf(st[1][0], st[1][1]), fmaxf(st[1][2], st[1][3])));
    float tm2 = fmaxf(fmaxf(fmaxf(st[2][0], st[2][1]), fmaxf(st[2][2], st[2][3])),
                      fmaxf(fmaxf(st[3][0], st[3][1]), fmaxf(st[3][2], st[3][3])));
    tm = fmaxf(tm, tm2);
    tm = fmaxf(tm, __shfl_xor(tm, 16));
    tm = fmaxf(tm, __shfl_xor(tm, 32));
    const float mnew = fmaxf(mrun, tm);
    const float fac = __expf(mrun - mnew);
    mrun = mnew;
    float ps = 0.f;
#pragma unroll
    for (int n = 0; n < 4; n++)
#pragma unroll
      for (int r = 0; r < 4; r++) {
        float p = __expf(st[n][r] - mnew);
        st[n][r] = p;
        ps += p;
      }
    ps += __shfl_xor(ps, 16);
    ps += __shfl_xor(ps, 32);
    lrun = lrun * fac + ps;
#pragma unroll
    for (int t = 0; t < 4; t++)
#pragma unroll
      for (int r = 0; r < 4; r++) oacc[t][r] *= fac;

    // ---- pack P rows to bf16 pairs ----
    unsigned pk[4][2];
#pragma unroll
    for (int n = 0; n < 4; n++) {
      pk[n][0] = pack2bf(st[n][0], st[n][1]);
      pk[n][1] = pack2bf(st[n][2], st[n][3]);
    }

    // ---- prefetch K for next kv tile (wraps to 0 on last iter) ----
    const int nkv = (kv + 64) & (SEQ - 1);
#pragma unroll
    for (int n = 0; n < 4; n++)
#pragma unroll
      for (int kk = 0; kk < 2; kk++)
        kf[n][kk] = *(const bf16x8*)&Kp[(size_t)(nkv + n * 16 + lrow) * DH + kk * 32 + lk * 8];

    // ---- in-register P transpose: gather B-operand fragments ----
    unsigned gA[4][2], gB[4][2];
#pragma unroll
    for (int n = 0; n < 4; n++)
#pragma unroll
      for (int k2 = 0; k2 < 2; k2++) {
        gA[n][k2] = (unsigned)__shfl((int)pk[n][k2], srcA);
        gB[n][k2] = (unsigned)__shfl((int)pk[n][k2], srcB);
      }
    bf16x8 pf[2];
#pragma unroll
    for (int c = 0; c < 2; c++) {
      const int n0 = c * 2;
      uint32x4 w;
      w.x = hiN ? gA[n0 + 1][0] : gA[n0][0];
      w.y = hiN ? gA[n0 + 1][1] : gA[n0][1];
      w.z = hiN ? gB[n0 + 1][0] : gB[n0][0];
      w.w = hiN ? gB[n0 + 1][1] : gB[n0][1];
      pf[c] = __builtin_bit_cast(bf16x8, w);
    }

    // ---- O^T += V^T P^T ----
#pragma unroll
    for (int t = 0; t < 4; t++)
#pragma unroll
      for (int c = 0; c < 2; c++)
        oacc[t] = __builtin_amdgcn_mfma_f32_16x16x32_bf16(vf[t][c], pf[c], oacc[t], 0, 0, 0);
  }

  // ---- epilogue: lane owns q-row (qrow0+lrow), d = t*16+lk*4+r ----
  const float inv = 1.f / lrun;
  __hip_bfloat16* Op = (__hip_bfloat16*)O;
  const size_t rowOff = (size_t)(b * SEQ + qrow0 + lrow) * C_DIM + h * DH;
#pragma unroll
  for (int t = 0; t < 4; t++) {
    ushort4 w;
    w.x = f2bf(oacc[t][0] * inv);
    w.y = f2bf(oacc[t][1] * inv);
    w.z = f2bf(oacc[t][2] * inv);
    w.w = f2bf(oacc[t][3] * inv);
    *(ushort4*)&Op[rowOff + t * 16 + lk * 4] = w;
  }
}

// ---------------------------------------------------------------------------
// 5) output projection + bias + residual -> fp32 X
// ---------------------------------------------------------------------------
__global__ __launch_bounds__(256) void gemm_out_kernel(
    const ushort_t* __restrict__ Obf, const ushort_t* __restrict__ Wot,
    const float* __restrict__ bo, const float* __restrict__ query,
    float* __restrict__ X) {
  __shared__ __align__(16) ushort_t ldsA[128 * 32];
  __shared__ __align__(16) ushort_t ldsB[128 * 32];
  const int rowBase = blockIdx.y * 128;
  const int colBase = blockIdx.x * 128;
  f32x4 acc[4][4];
#pragma unroll
  for (int m = 0; m < 4; m++)
#pragma unroll
    for (int n = 0; n < 4; n++)
#pragma unroll
      for (int r = 0; r < 4; r++) acc[m][n][r] = 0.f;

  gemm128_mainloop(Obf, Wot, rowBase, colBase, ldsA, ldsB, acc);

  const int lane = threadIdx.x & 63, wave = threadIdx.x >> 6;
  const int wr = wave >> 1, wc = wave & 1;
  const int lrow = lane & 15, lk = lane >> 4;
#pragma unroll
  for (int n = 0; n < 4; n++) {
    const int col = colBase + wc * 64 + n * 16 + lrow;
    const float bval = bo[col];
#pragma unroll
    for (int m = 0; m < 4; m++) {
#pragma unroll
      for (int r = 0; r < 4; r++) {
        const int row = rowBase + wr * 64 + m * 16 + lk * 4 + r;
        const size_t idx = (size_t)row * C_DIM + col;
        X[idx] = acc[m][n][r] + bval + query[idx];
      }
    }
  }
}

// ---------------------------------------------------------------------------
// 6) LayerNorm over rows of X -> d_out (fp32)
// ---------------------------------------------------------------------------
__global__ __launch_bounds__(256) void ln_kernel(
    const float* __restrict__ X, const float* __restrict__ gamma,
    const float* __restrict__ beta, float* __restrict__ out) {
  const int row = blockIdx.x, tid = threadIdx.x;
  const float* xr = X + (size_t)row * C_DIM;
  float x0 = xr[tid], x1 = xr[tid + 256], x2 = xr[tid + 512];
  float s = x0 + x1 + x2;
  float sq = x0 * x0 + x1 * x1 + x2 * x2;
#pragma unroll
  for (int off = 32; off; off >>= 1) {
    s  += __shfl_xor(s, off);
    sq += __shfl_xor(sq, off);
  }
  __shared__ float as_[4], aq_[4];
  if ((tid & 63) == 0) { as_[tid >> 6] = s; aq_[tid >> 6] = sq; }
  __syncthreads();
  s  = as_[0] + as_[1] + as_[2] + as_[3];
  sq = aq_[0] + aq_[1] + aq_[2] + aq_[3];
  const float mean = s * (1.f / C_DIM);
  const float var  = sq * (1.f / C_DIM) - mean * mean;
  const float rstd = rsqrtf(var + EPS);
  float* orow = out + (size_t)row * C_DIM;
  orow[tid]       = (x0 - mean) * rstd * gamma[tid]       + beta[tid];
  orow[tid + 256] = (x1 - mean) * rstd * gamma[tid + 256] + beta[tid + 256];
  orow[tid + 512] = (x2 - mean) * rstd * gamma[tid + 512] + beta[tid + 512];
}

// ---------------------------------------------------------------------------
extern "C" void kernel_launch(void* const* d_in, const int* in_sizes, int n_in,
                              void* d_out, int out_size, void* d_ws, size_t ws_size,
                              hipStream_t stream) {
  (void)in_sizes; (void)n_in; (void)out_size; (void)ws_size;
  const float* query  = (const float*)d_in[0];
  const float* key_in = (const float*)d_in[1];
  const float* value  = (const float*)d_in[2];
  const float* Wq = (const float*)d_in[3];
  const float* bq = (const float*)d_in[4];
  const float* Wk = (const float*)d_in[5];
  const float* bk = (const float*)d_in[6];
  const float* Wv = (const float*)d_in[7];
  const float* bv = (const float*)d_in[8];
  const float* Wo = (const float*)d_in[9];
  const float* bo = (const float*)d_in[10];
  const float* gamma = (const float*)d_in[11];
  const float* beta  = (const float*)d_in[12];

  char* ws = (char*)d_ws;
  ushort_t* Xq  = (ushort_t*)(ws + B_XQ);
  ushort_t* Xk  = (ushort_t*)(ws + B_XK);
  ushort_t* Xv  = (ushort_t*)(ws + B_XV);
  ushort_t* Wqt = (ushort_t*)(ws + B_WQT);
  ushort_t* Wkt = (ushort_t*)(ws + B_WKT);
  ushort_t* Wvt = (ushort_t*)(ws + B_WVT);
  ushort_t* Wot = (ushort_t*)(ws + B_WOT);
  ushort_t* Qh  = (ushort_t*)(ws + B_QH);
  ushort_t* Kh  = (ushort_t*)(ws + B_KH);
  ushort_t* Vt  = (ushort_t*)(ws + B_VT);
  ushort_t* Obf = (ushort_t*)(ws + B_O);
  float*    Xr  = (float*)(ws + B_XR);
  float*    out = (float*)d_out;

  const int n4 = (int)(SZ_X / 4);            // 786432
  cvt3_kernel<<<dim3(n4 / 256, 3), 256, 0, stream>>>(query, key_in, value,
                                                     Xq, Xk, Xv, n4);

  wtrans_kernel<<<dim3(24, 24, 4), 256, 0, stream>>>(Wq, Wk, Wv, Wo, Wqt, Wkt, Wvt, Wot);

  gemm_qkv_kernel<<<dim3(6, 32, 3), 256, 0, stream>>>(Xq, Xk, Xv, Wqt, Wkt, Wvt,
                                                      bq, bk, bv, Qh, Kh, Vt);

  attn_kernel<<<dim3(32, 24), 256, 0, stream>>>(Qh, Kh, Vt, Obf);

  gemm_out_kernel<<<dim3(6, 32), 256, 0, stream>>>(Obf, Wot, bo, query, Xr);

  ln_kernel<<<MTOT, 256, 0, stream>>>(Xr, gamma, beta, out);
}

// Round 5
// 290.747 us; speedup vs baseline: 1.2358x; 1.2358x over previous
//
#include <hip/hip_runtime.h>
#include <hip/hip_bf16.h>

// ---------------------------------------------------------------------------
// CrossAttention block: softmax(QK^T/sqrt(d)) V, out-proj, residual, LayerNorm
// B=2, N=2048, C=768, H=12, Dh=64.  bf16 MFMA everywhere, fp32 accumulation.
// R3: attention rebuilt on 32x32x16 MFMA (m214 structure): swapped QK^T,
//     permlane32_swap softmax reduce, cvt_pk+permlane in-register P transpose,
//     defer-max rescale, register K double-buffer.  No LDS, no ds_bpermute.
// (resubmitted unchanged after R3/R4 GPU-acquisition timeouts)
// ---------------------------------------------------------------------------

typedef unsigned short ushort_t;
typedef __bf16 bf16x8 __attribute__((ext_vector_type(8)));
typedef float  f32x4  __attribute__((ext_vector_type(4)));
typedef float  f32x16 __attribute__((ext_vector_type(16)));
typedef unsigned int uint32x4 __attribute__((ext_vector_type(4)));
typedef int    i32x2  __attribute__((ext_vector_type(2)));

constexpr int C_DIM  = 768;
constexpr int HEADS  = 12;
constexpr int DH     = 64;
constexpr int BATCH  = 2;
constexpr int SEQ    = 2048;
constexpr int MTOT   = BATCH * SEQ;      // 4096 rows
constexpr float EPS  = 1e-5f;
constexpr float SCALE = 0.125f;          // Dh^-0.5 = 1/8 (folded into Q proj)

// workspace layout (bytes)
constexpr size_t SZ_X = (size_t)MTOT * C_DIM;
constexpr size_t SZ_W = (size_t)C_DIM * C_DIM;
constexpr size_t B_XQ  = 0;
constexpr size_t B_XK  = B_XQ  + SZ_X * 2;
constexpr size_t B_XV  = B_XK  + SZ_X * 2;
constexpr size_t B_WQT = B_XV  + SZ_X * 2;
constexpr size_t B_WKT = B_WQT + SZ_W * 2;
constexpr size_t B_WVT = B_WKT + SZ_W * 2;
constexpr size_t B_WOT = B_WVT + SZ_W * 2;
constexpr size_t B_QH  = B_WOT + SZ_W * 2;      // [B,H,N,DH] bf16 (pre-scaled)
constexpr size_t B_KH  = B_QH  + SZ_X * 2;      // [B,H,N,DH] bf16
constexpr size_t B_VT  = B_KH  + SZ_X * 2;      // [B,H,DH,N] bf16 (transposed)
constexpr size_t B_O   = B_VT  + SZ_X * 2;      // [MTOT,C] bf16 attn output
constexpr size_t B_XR  = B_O   + SZ_X * 2;      // [MTOT,C] fp32 pre-LN

__device__ __forceinline__ ushort_t f2bf(float f) {
  __hip_bfloat16 h = __float2bfloat16(f);
  return __builtin_bit_cast(unsigned short, h);
}

// hardware packed f32x2 -> bf16x2 convert (RNE), one VALU inst
__device__ __forceinline__ unsigned cvtpk(float lo, float hi) {
  unsigned r;
  asm("v_cvt_pk_bf16_f32 %0, %1, %2" : "=v"(r) : "v"(lo), "v"(hi));
  return r;
}
// cross-half (lane l <-> l+32) max / sum via permlane32_swap (VALU pipe)
__device__ __forceinline__ float xhalf_max(float x) {
  i32x2 r = __builtin_amdgcn_permlane32_swap(
      __builtin_bit_cast(int, x), __builtin_bit_cast(int, x), false, false);
  return fmaxf(__builtin_bit_cast(float, r.x), __builtin_bit_cast(float, r.y));
}
__device__ __forceinline__ float xhalf_sum(float x) {
  i32x2 r = __builtin_amdgcn_permlane32_swap(
      __builtin_bit_cast(int, x), __builtin_bit_cast(int, x), false, false);
  return __builtin_bit_cast(float, r.x) + __builtin_bit_cast(float, r.y);
}

// async global->LDS, 16B per lane.  LDS dest must be linear (base + lane*16).
__device__ __forceinline__ void gload_lds16(const void* g, void* l) {
  __builtin_amdgcn_global_load_lds(
      (const __attribute__((address_space(1))) unsigned int*)g,
      (__attribute__((address_space(3))) unsigned int*)l,
      16, 0, 0);
}

// ---------------------------------------------------------------------------
// 1) fp32 -> bf16 elementwise convert, all three activations in one launch
// ---------------------------------------------------------------------------
__global__ __launch_bounds__(256) void cvt3_kernel(
    const float* __restrict__ s0, const float* __restrict__ s1,
    const float* __restrict__ s2,
    ushort_t* __restrict__ d0, ushort_t* __restrict__ d1,
    ushort_t* __restrict__ d2, int n4) {
  const float* src = blockIdx.y == 0 ? s0 : blockIdx.y == 1 ? s1 : s2;
  ushort_t*    dst = blockIdx.y == 0 ? d0 : blockIdx.y == 1 ? d1 : d2;
  int i = blockIdx.x * 256 + threadIdx.x;
  if (i >= n4) return;
  float4 v = ((const float4*)src)[i];
  ushort4 o;
  o.x = f2bf(v.x); o.y = f2bf(v.y); o.z = f2bf(v.z); o.w = f2bf(v.w);
  ((ushort4*)dst)[i] = o;
}

// ---------------------------------------------------------------------------
// 2) transpose+convert the 4 weight matrices:  Wt[n][k] = W[k][n]  (bf16)
// ---------------------------------------------------------------------------
__global__ __launch_bounds__(256) void wtrans_kernel(
    const float* __restrict__ W0, const float* __restrict__ W1,
    const float* __restrict__ W2, const float* __restrict__ W3,
    ushort_t* T0, ushort_t* T1, ushort_t* T2, ushort_t* T3) {
  const float* W = blockIdx.z == 0 ? W0 : blockIdx.z == 1 ? W1 : blockIdx.z == 2 ? W2 : W3;
  ushort_t*    T = blockIdx.z == 0 ? T0 : blockIdx.z == 1 ? T1 : blockIdx.z == 2 ? T2 : T3;
  __shared__ float tile[32][33];
  int tx = threadIdx.x & 31, ty = threadIdx.x >> 5;   // 32 x 8
  int x0 = blockIdx.x * 32, y0 = blockIdx.y * 32;
#pragma unroll
  for (int i = 0; i < 32; i += 8)
    tile[ty + i][tx] = W[(size_t)(y0 + ty + i) * C_DIM + x0 + tx];
  __syncthreads();
#pragma unroll
  for (int i = 0; i < 32; i += 8)
    T[(size_t)(x0 + ty + i) * C_DIM + y0 + tx] = f2bf(tile[tx][ty + i]);
}

// ---------------------------------------------------------------------------
// GEMM mainloop: C[128x128] = A[128xK] * Bt[128xK]^T, K=768, BK=32.
// ---------------------------------------------------------------------------
__device__ __forceinline__ void gemm128_mainloop(
    const ushort_t* __restrict__ A, const ushort_t* __restrict__ Bt,
    int rowBase, int colBase, ushort_t* ldsA, ushort_t* ldsB, f32x4 acc[4][4]) {
  const int tid = threadIdx.x;
  const int wave = tid >> 6, lane = tid & 63;
  const int wr = wave >> 1, wc = wave & 1;
  const int lrow = lane & 15, lk = lane >> 4;
  const int sr = tid >> 2, sk = (tid & 3) * 8;
  const int K = C_DIM;

  const ushort_t* ga0 = A  + (size_t)(rowBase + sr)      * K + sk;
  const ushort_t* ga1 = A  + (size_t)(rowBase + 64 + sr) * K + sk;
  const ushort_t* gb0 = Bt + (size_t)(colBase + sr)      * K + sk;
  const ushort_t* gb1 = Bt + (size_t)(colBase + 64 + sr) * K + sk;
  ushort_t* la = ldsA + sr * 32 + sk;
  ushort_t* lb = ldsB + sr * 32 + sk;

  for (int kt = 0; kt < K; kt += 32) {
    gload_lds16(ga0 + kt, la);
    gload_lds16(ga1 + kt, la + 64 * 32);
    gload_lds16(gb0 + kt, lb);
    gload_lds16(gb1 + kt, lb + 64 * 32);
    asm volatile("s_waitcnt vmcnt(0)" ::: "memory");
    __syncthreads();
    bf16x8 af[4], bfr[4];
#pragma unroll
    for (int m = 0; m < 4; m++)
      af[m] = *(const bf16x8*)(ldsA + (wr * 64 + m * 16 + lrow) * 32 + lk * 8);
#pragma unroll
    for (int n = 0; n < 4; n++)
      bfr[n] = *(const bf16x8*)(ldsB + (wc * 64 + n * 16 + lrow) * 32 + lk * 8);
#pragma unroll
    for (int m = 0; m < 4; m++)
#pragma unroll
      for (int n = 0; n < 4; n++)
        acc[m][n] = __builtin_amdgcn_mfma_f32_16x16x32_bf16(af[m], bfr[n], acc[m][n], 0, 0, 0);
    __syncthreads();
  }
}

// ---------------------------------------------------------------------------
// 3) fused QKV projection.  grid = (6 colTiles, 32 rowTiles, 3 matrices)
// ---------------------------------------------------------------------------
__global__ __launch_bounds__(256) void gemm_qkv_kernel(
    const ushort_t* __restrict__ Xq, const ushort_t* __restrict__ Xk,
    const ushort_t* __restrict__ Xv,
    const ushort_t* __restrict__ Wqt, const ushort_t* __restrict__ Wkt,
    const ushort_t* __restrict__ Wvt,
    const float* __restrict__ bq, const float* __restrict__ bk,
    const float* __restrict__ bv,
    ushort_t* Qh, ushort_t* Kh, ushort_t* Vt) {
  const int mat = blockIdx.z;
  const ushort_t* A  = mat == 0 ? Xq  : mat == 1 ? Xk  : Xv;
  const ushort_t* Bt = mat == 0 ? Wqt : mat == 1 ? Wkt : Wvt;
  const float* bias  = mat == 0 ? bq  : mat == 1 ? bk  : bv;

  __shared__ __align__(16) ushort_t ldsA[128 * 32];
  __shared__ __align__(16) ushort_t ldsB[128 * 32];

  const int rowBase = blockIdx.y * 128;
  const int colBase = blockIdx.x * 128;
  f32x4 acc[4][4];
#pragma unroll
  for (int m = 0; m < 4; m++)
#pragma unroll
    for (int n = 0; n < 4; n++)
#pragma unroll
      for (int r = 0; r < 4; r++) acc[m][n][r] = 0.f;

  gemm128_mainloop(A, Bt, rowBase, colBase, ldsA, ldsB, acc);

  const int lane = threadIdx.x & 63, wave = threadIdx.x >> 6;
  const int wr = wave >> 1, wc = wave & 1;
  const int lrow = lane & 15, lk = lane >> 4;
  const float sc = (mat == 0) ? SCALE : 1.0f;

  __hip_bfloat16* dqk = (__hip_bfloat16*)(mat == 0 ? Qh : Kh);
  __hip_bfloat16* dvt = (__hip_bfloat16*)Vt;
#pragma unroll
  for (int n = 0; n < 4; n++) {
    const int col = colBase + wc * 64 + n * 16 + lrow;
    const float bval = bias[col];
    const int hh = col >> 6, dd = col & 63;
#pragma unroll
    for (int m = 0; m < 4; m++) {
#pragma unroll
      for (int r = 0; r < 4; r++) {
        const int row = rowBase + wr * 64 + m * 16 + lk * 4 + r;
        const int bb = row >> 11, nn = row & 2047;
        const float val = (acc[m][n][r] + bval) * sc;
        if (mat < 2) {
          dqk[(((size_t)(bb * HEADS + hh) * SEQ + nn) << 6) + dd] = __float2bfloat16(val);
        } else {
          dvt[((size_t)(bb * HEADS + hh) * DH + dd) * SEQ + nn] = __float2bfloat16(val);
        }
      }
    }
  }
}

// ---------------------------------------------------------------------------
// 4) flash attention, 32x32 MFMA swapped form (m214 structure).
//    grid = (16 qTiles, 24 bh).  4 waves x 32 q-rows, waves independent.
//    S^T = mfma32(K_frag, Q^T_frag): lane l holds S[q=l&31][kv rows
//      {(r&3)+8*(r>>2)+4*(l>>5)}].  Softmax reduce: 15 fmax + 1 permlane swap.
//    P -> PV B-operand: 8 cvt_pk + 4 permlane32_swap, fully in-register.
//    O^T accumulated per d-tile; defer-max (THR=8) skips most rescales.
// ---------------------------------------------------------------------------
__global__ __launch_bounds__(256) void attn_kernel(
    const ushort_t* __restrict__ Qh, const ushort_t* __restrict__ Kh,
    const ushort_t* __restrict__ Vt, ushort_t* __restrict__ O) {
  const int bh = blockIdx.y;          // 0..23
  const int b = bh / HEADS, h = bh % HEADS;
  const ushort_t* Qp = Qh + (size_t)bh * SEQ * DH;
  const ushort_t* Kp = Kh + (size_t)bh * SEQ * DH;
  const ushort_t* Vp = Vt + (size_t)bh * DH * SEQ;

  const int tid = threadIdx.x, wave = tid >> 6, lane = tid & 63;
  const int lq = lane & 31;           // q-row (and K/V row) index within tile
  const int hi = lane >> 5;           // lane half
  const int qrow0 = (blockIdx.x * 4 + wave) * 32;

  // Q B-frags (pre-scaled by 1/8): qf[ks] = Q[qrow0+lq][ks*16 + hi*8 + j]
  bf16x8 qf[4];
#pragma unroll
  for (int ks = 0; ks < 4; ks++)
    qf[ks] = *(const bf16x8*)&Qp[(size_t)(qrow0 + lq) * DH + ks * 16 + hi * 8];

  // K A-frags, register double-buffer
  bf16x8 kfA[4], kfB[4];
#pragma unroll
  for (int ks = 0; ks < 4; ks++)
    kfA[ks] = *(const bf16x8*)&Kp[(size_t)lq * DH + ks * 16 + hi * 8];

  f32x16 oacc[2];
#pragma unroll
  for (int dt = 0; dt < 2; dt++)
#pragma unroll
    for (int r = 0; r < 16; r++) oacc[dt][r] = 0.f;
  float mrun = -3e38f, lrun = 0.f;

#pragma unroll 1
  for (int it = 0; it < SEQ / 32; it++) {
    const int kv = it * 32;
    const bf16x8* kc = (it & 1) ? kfB : kfA;
    bf16x8*       kn = (it & 1) ? kfA : kfB;

    // ---- S^T = K Q^T (32x32 tile, Dh=64 -> 4 chained mfma) ----
    f32x16 st;
#pragma unroll
    for (int r = 0; r < 16; r++) st[r] = 0.f;
#pragma unroll
    for (int ks = 0; ks < 4; ks++)
      st = __builtin_amdgcn_mfma_f32_32x32x16_bf16(kc[ks], qf[ks], st, 0, 0, 0);

    // ---- V frags for THIS tile (issued now, consumed after softmax) ----
    bf16x8 vf[2][2];
#pragma unroll
    for (int dt = 0; dt < 2; dt++)
#pragma unroll
      for (int s = 0; s < 2; s++)
        vf[dt][s] = *(const bf16x8*)&Vp[(size_t)(dt * 32 + lq) * SEQ + kv + s * 16 + hi * 8];

    // ---- prefetch next K tile into the other register buffer ----
    const int nkv = (kv + 32) & (SEQ - 1);
#pragma unroll
    for (int ks = 0; ks < 4; ks++)
      kn[ks] = *(const bf16x8*)&Kp[(size_t)(nkv + lq) * DH + ks * 16 + hi * 8];

    // ---- online softmax: row q = lq, split across lane pair (l, l+32) ----
    float tm = st[0];
#pragma unroll
    for (int r = 1; r < 16; r++) tm = fmaxf(tm, st[r]);
    tm = xhalf_max(tm);
    float m = mrun;
    if (!__all(tm <= mrun + 8.f)) {           // defer-max (T13)
      m = fmaxf(mrun, tm);
      const float fac = __expf(mrun - m);
      mrun = m;
      lrun *= fac;
#pragma unroll
      for (int dt = 0; dt < 2; dt++)
#pragma unroll
        for (int r = 0; r < 16; r++) oacc[dt][r] *= fac;
    }
    float ps = 0.f;
#pragma unroll
    for (int r = 0; r < 16; r++) {
      float p = __expf(st[r] - m);
      st[r] = p;
      ps += p;
    }
    lrun += xhalf_sum(ps);

    // ---- P -> bf16 B-operand frags: 8 cvt_pk + 4 permlane32_swap (T12) ----
    unsigned pk[8];
#pragma unroll
    for (int i = 0; i < 8; i++) pk[i] = cvtpk(st[2 * i], st[2 * i + 1]);
    uint32x4 a0, a1;
    {
      i32x2 r02 = __builtin_amdgcn_permlane32_swap((int)pk[0], (int)pk[2], false, false);
      i32x2 r13 = __builtin_amdgcn_permlane32_swap((int)pk[1], (int)pk[3], false, false);
      a0.x = (unsigned)r02.x; a0.y = (unsigned)r13.x;
      a0.z = (unsigned)r02.y; a0.w = (unsigned)r13.y;
      i32x2 r46 = __builtin_amdgcn_permlane32_swap((int)pk[4], (int)pk[6], false, false);
      i32x2 r57 = __builtin_amdgcn_permlane32_swap((int)pk[5], (int)pk[7], false, false);
      a1.x = (unsigned)r46.x; a1.y = (unsigned)r57.x;
      a1.z = (unsigned)r46.y; a1.w = (unsigned)r57.y;
    }
    const bf16x8 w0 = __builtin_bit_cast(bf16x8, a0);
    const bf16x8 w1 = __builtin_bit_cast(bf16x8, a1);

    // ---- O^T += V^T P^T ----
#pragma unroll
    for (int dt = 0; dt < 2; dt++) {
      oacc[dt] = __builtin_amdgcn_mfma_f32_32x32x16_bf16(vf[dt][0], w0, oacc[dt], 0, 0, 0);
      oacc[dt] = __builtin_amdgcn_mfma_f32_32x32x16_bf16(vf[dt][1], w1, oacc[dt], 0, 0, 0);
    }
  }

  // ---- epilogue: lane owns q-row qrow0+lq; d = dt*32 + 8g + 4hi + r ----
  const float inv = 1.f / lrun;
  __hip_bfloat16* Op = (__hip_bfloat16*)O;
  const size_t rowOff = (size_t)(b * SEQ + qrow0 + lq) * C_DIM + h * DH;
#pragma unroll
  for (int dt = 0; dt < 2; dt++)
#pragma unroll
    for (int g = 0; g < 4; g++) {
      ushort4 w;
      w.x = f2bf(oacc[dt][g * 4 + 0] * inv);
      w.y = f2bf(oacc[dt][g * 4 + 1] * inv);
      w.z = f2bf(oacc[dt][g * 4 + 2] * inv);
      w.w = f2bf(oacc[dt][g * 4 + 3] * inv);
      *(ushort4*)&Op[rowOff + dt * 32 + g * 8 + hi * 4] = w;
    }
}

// ---------------------------------------------------------------------------
// 5) output projection + bias + residual -> fp32 X
// ---------------------------------------------------------------------------
__global__ __launch_bounds__(256) void gemm_out_kernel(
    const ushort_t* __restrict__ Obf, const ushort_t* __restrict__ Wot,
    const float* __restrict__ bo, const float* __restrict__ query,
    float* __restrict__ X) {
  __shared__ __align__(16) ushort_t ldsA[128 * 32];
  __shared__ __align__(16) ushort_t ldsB[128 * 32];
  const int rowBase = blockIdx.y * 128;
  const int colBase = blockIdx.x * 128;
  f32x4 acc[4][4];
#pragma unroll
  for (int m = 0; m < 4; m++)
#pragma unroll
    for (int n = 0; n < 4; n++)
#pragma unroll
      for (int r = 0; r < 4; r++) acc[m][n][r] = 0.f;

  gemm128_mainloop(Obf, Wot, rowBase, colBase, ldsA, ldsB, acc);

  const int lane = threadIdx.x & 63, wave = threadIdx.x >> 6;
  const int wr = wave >> 1, wc = wave & 1;
  const int lrow = lane & 15, lk = lane >> 4;
#pragma unroll
  for (int n = 0; n < 4; n++) {
    const int col = colBase + wc * 64 + n * 16 + lrow;
    const float bval = bo[col];
#pragma unroll
    for (int m = 0; m < 4; m++) {
#pragma unroll
      for (int r = 0; r < 4; r++) {
        const int row = rowBase + wr * 64 + m * 16 + lk * 4 + r;
        const size_t idx = (size_t)row * C_DIM + col;
        X[idx] = acc[m][n][r] + bval + query[idx];
      }
    }
  }
}

// ---------------------------------------------------------------------------
// 6) LayerNorm over rows of X -> d_out (fp32)
// ---------------------------------------------------------------------------
__global__ __launch_bounds__(256) void ln_kernel(
    const float* __restrict__ X, const float* __restrict__ gamma,
    const float* __restrict__ beta, float* __restrict__ out) {
  const int row = blockIdx.x, tid = threadIdx.x;
  const float* xr = X + (size_t)row * C_DIM;
  float x0 = xr[tid], x1 = xr[tid + 256], x2 = xr[tid + 512];
  float s = x0 + x1 + x2;
  float sq = x0 * x0 + x1 * x1 + x2 * x2;
#pragma unroll
  for (int off = 32; off; off >>= 1) {
    s  += __shfl_xor(s, off);
    sq += __shfl_xor(sq, off);
  }
  __shared__ float as_[4], aq_[4];
  if ((tid & 63) == 0) { as_[tid >> 6] = s; aq_[tid >> 6] = sq; }
  __syncthreads();
  s  = as_[0] + as_[1] + as_[2] + as_[3];
  sq = aq_[0] + aq_[1] + aq_[2] + aq_[3];
  const float mean = s * (1.f / C_DIM);
  const float var  = sq * (1.f / C_DIM) - mean * mean;
  const float rstd = rsqrtf(var + EPS);
  float* orow = out + (size_t)row * C_DIM;
  orow[tid]       = (x0 - mean) * rstd * gamma[tid]       + beta[tid];
  orow[tid + 256] = (x1 - mean) * rstd * gamma[tid + 256] + beta[tid + 256];
  orow[tid + 512] = (x2 - mean) * rstd * gamma[tid + 512] + beta[tid + 512];
}

// ---------------------------------------------------------------------------
extern "C" void kernel_launch(void* const* d_in, const int* in_sizes, int n_in,
                              void* d_out, int out_size, void* d_ws, size_t ws_size,
                              hipStream_t stream) {
  (void)in_sizes; (void)n_in; (void)out_size; (void)ws_size;
  const float* query  = (const float*)d_in[0];
  const float* key_in = (const float*)d_in[1];
  const float* value  = (const float*)d_in[2];
  const float* Wq = (const float*)d_in[3];
  const float* bq = (const float*)d_in[4];
  const float* Wk = (const float*)d_in[5];
  const float* bk = (const float*)d_in[6];
  const float* Wv = (const float*)d_in[7];
  const float* bv = (const float*)d_in[8];
  const float* Wo = (const float*)d_in[9];
  const float* bo = (const float*)d_in[10];
  const float* gamma = (const float*)d_in[11];
  const float* beta  = (const float*)d_in[12];

  char* ws = (char*)d_ws;
  ushort_t* Xq  = (ushort_t*)(ws + B_XQ);
  ushort_t* Xk  = (ushort_t*)(ws + B_XK);
  ushort_t* Xv  = (ushort_t*)(ws + B_XV);
  ushort_t* Wqt = (ushort_t*)(ws + B_WQT);
  ushort_t* Wkt = (ushort_t*)(ws + B_WKT);
  ushort_t* Wvt = (ushort_t*)(ws + B_WVT);
  ushort_t* Wot = (ushort_t*)(ws + B_WOT);
  ushort_t* Qh  = (ushort_t*)(ws + B_QH);
  ushort_t* Kh  = (ushort_t*)(ws + B_KH);
  ushort_t* Vt  = (ushort_t*)(ws + B_VT);
  ushort_t* Obf = (ushort_t*)(ws + B_O);
  float*    Xr  = (float*)(ws + B_XR);
  float*    out = (float*)d_out;

  const int n4 = (int)(SZ_X / 4);
  cvt3_kernel<<<dim3(n4 / 256, 3), 256, 0, stream>>>(query, key_in, value,
                                                     Xq, Xk, Xv, n4);

  wtrans_kernel<<<dim3(24, 24, 4), 256, 0, stream>>>(Wq, Wk, Wv, Wo, Wqt, Wkt, Wvt, Wot);

  gemm_qkv_kernel<<<dim3(6, 32, 3), 256, 0, stream>>>(Xq, Xk, Xv, Wqt, Wkt, Wvt,
                                                      bq, bk, bv, Qh, Kh, Vt);

  attn_kernel<<<dim3(SEQ / 128, BATCH * HEADS), 256, 0, stream>>>(Qh, Kh, Vt, Obf);

  gemm_out_kernel<<<dim3(6, 32), 256, 0, stream>>>(Obf, Wot, bo, query, Xr);

  ln_kernel<<<MTOT, 256, 0, stream>>>(Xr, gamma, beta, out);
}

// Round 6
// 277.650 us; speedup vs baseline: 1.2941x; 1.0472x over previous
//
#include <hip/hip_runtime.h>
#include <hip/hip_bf16.h>

// ---------------------------------------------------------------------------
// CrossAttention block: softmax(QK^T/sqrt(d)) V, out-proj, residual, LayerNorm
// B=2, N=2048, C=768, H=12, Dh=64.  bf16 MFMA everywhere, fp32 accumulation.
// R6: attention gets (1) XCD-aware block swizzle so each head's K/V stays in
//     one XCD's L2, (2) kv-split x2 with bf16 partial-O + (m,l) combine pass
//     for 2x wave-level parallelism, (3) s_setprio around MFMA clusters.
// ---------------------------------------------------------------------------

typedef unsigned short ushort_t;
typedef __bf16 bf16x8 __attribute__((ext_vector_type(8)));
typedef float  f32x4  __attribute__((ext_vector_type(4)));
typedef float  f32x16 __attribute__((ext_vector_type(16)));
typedef unsigned int uint32x4 __attribute__((ext_vector_type(4)));
typedef int    i32x2  __attribute__((ext_vector_type(2)));

constexpr int C_DIM  = 768;
constexpr int HEADS  = 12;
constexpr int DH     = 64;
constexpr int BATCH  = 2;
constexpr int SEQ    = 2048;
constexpr int MTOT   = BATCH * SEQ;          // 4096 rows of X
constexpr int MROWS  = BATCH * HEADS * SEQ;  // 49152 attention rows
constexpr int NSPLIT = 2;
constexpr int KVSPAN = SEQ / NSPLIT;         // 1024 kv per split
constexpr float EPS  = 1e-5f;
constexpr float SCALE = 0.125f;              // Dh^-0.5 (folded into Q proj)

// workspace layout (bytes)
constexpr size_t SZ_X = (size_t)MTOT * C_DIM;
constexpr size_t SZ_W = (size_t)C_DIM * C_DIM;
constexpr size_t B_XQ  = 0;
constexpr size_t B_XK  = B_XQ  + SZ_X * 2;
constexpr size_t B_XV  = B_XK  + SZ_X * 2;
constexpr size_t B_WQT = B_XV  + SZ_X * 2;
constexpr size_t B_WKT = B_WQT + SZ_W * 2;
constexpr size_t B_WVT = B_WKT + SZ_W * 2;
constexpr size_t B_WOT = B_WVT + SZ_W * 2;
constexpr size_t B_QH  = B_WOT + SZ_W * 2;      // [B,H,N,DH] bf16 (pre-scaled)
constexpr size_t B_KH  = B_QH  + SZ_X * 2;      // [B,H,N,DH] bf16
constexpr size_t B_VT  = B_KH  + SZ_X * 2;      // [B,H,DH,N] bf16 (transposed)
constexpr size_t B_O   = B_VT  + SZ_X * 2;      // [MTOT,C] bf16 attn output
constexpr size_t B_XR  = B_O   + SZ_X * 2;      // [MTOT,C] fp32 pre-LN
// attn partials OVERLAY the Xq/Xk/Xv region (dead after gemm_qkv):
constexpr size_t B_OP  = B_XQ;                              // [2][MROWS][64] bf16
constexpr size_t B_ML  = B_OP + (size_t)NSPLIT * MROWS * DH * 2;  // [2][MROWS] float2
// end = 12.58MB + 0.79MB = 13.4MB < 18.9MB (Xq..Xv region)  ✓

__device__ __forceinline__ ushort_t f2bf(float f) {
  __hip_bfloat16 h = __float2bfloat16(f);
  return __builtin_bit_cast(unsigned short, h);
}

// hardware packed f32x2 -> bf16x2 convert (RNE), one VALU inst
__device__ __forceinline__ unsigned cvtpk(float lo, float hi) {
  unsigned r;
  asm("v_cvt_pk_bf16_f32 %0, %1, %2" : "=v"(r) : "v"(lo), "v"(hi));
  return r;
}
// cross-half (lane l <-> l+32) max / sum via permlane32_swap (VALU pipe)
__device__ __forceinline__ float xhalf_max(float x) {
  i32x2 r = __builtin_amdgcn_permlane32_swap(
      __builtin_bit_cast(int, x), __builtin_bit_cast(int, x), false, false);
  return fmaxf(__builtin_bit_cast(float, r.x), __builtin_bit_cast(float, r.y));
}
__device__ __forceinline__ float xhalf_sum(float x) {
  i32x2 r = __builtin_amdgcn_permlane32_swap(
      __builtin_bit_cast(int, x), __builtin_bit_cast(int, x), false, false);
  return __builtin_bit_cast(float, r.x) + __builtin_bit_cast(float, r.y);
}

// async global->LDS, 16B per lane.  LDS dest must be linear (base + lane*16).
__device__ __forceinline__ void gload_lds16(const void* g, void* l) {
  __builtin_amdgcn_global_load_lds(
      (const __attribute__((address_space(1))) unsigned int*)g,
      (__attribute__((address_space(3))) unsigned int*)l,
      16, 0, 0);
}

// ---------------------------------------------------------------------------
// 1) fp32 -> bf16 elementwise convert, all three activations in one launch
// ---------------------------------------------------------------------------
__global__ __launch_bounds__(256) void cvt3_kernel(
    const float* __restrict__ s0, const float* __restrict__ s1,
    const float* __restrict__ s2,
    ushort_t* __restrict__ d0, ushort_t* __restrict__ d1,
    ushort_t* __restrict__ d2, int n4) {
  const float* src = blockIdx.y == 0 ? s0 : blockIdx.y == 1 ? s1 : s2;
  ushort_t*    dst = blockIdx.y == 0 ? d0 : blockIdx.y == 1 ? d1 : d2;
  int i = blockIdx.x * 256 + threadIdx.x;
  if (i >= n4) return;
  float4 v = ((const float4*)src)[i];
  ushort4 o;
  o.x = f2bf(v.x); o.y = f2bf(v.y); o.z = f2bf(v.z); o.w = f2bf(v.w);
  ((ushort4*)dst)[i] = o;
}

// ---------------------------------------------------------------------------
// 2) transpose+convert the 4 weight matrices:  Wt[n][k] = W[k][n]  (bf16)
// ---------------------------------------------------------------------------
__global__ __launch_bounds__(256) void wtrans_kernel(
    const float* __restrict__ W0, const float* __restrict__ W1,
    const float* __restrict__ W2, const float* __restrict__ W3,
    ushort_t* T0, ushort_t* T1, ushort_t* T2, ushort_t* T3) {
  const float* W = blockIdx.z == 0 ? W0 : blockIdx.z == 1 ? W1 : blockIdx.z == 2 ? W2 : W3;
  ushort_t*    T = blockIdx.z == 0 ? T0 : blockIdx.z == 1 ? T1 : blockIdx.z == 2 ? T2 : T3;
  __shared__ float tile[32][33];
  int tx = threadIdx.x & 31, ty = threadIdx.x >> 5;   // 32 x 8
  int x0 = blockIdx.x * 32, y0 = blockIdx.y * 32;
#pragma unroll
  for (int i = 0; i < 32; i += 8)
    tile[ty + i][tx] = W[(size_t)(y0 + ty + i) * C_DIM + x0 + tx];
  __syncthreads();
#pragma unroll
  for (int i = 0; i < 32; i += 8)
    T[(size_t)(x0 + ty + i) * C_DIM + y0 + tx] = f2bf(tile[tx][ty + i]);
}

// ---------------------------------------------------------------------------
// GEMM mainloop: C[128x128] = A[128xK] * Bt[128xK]^T, K=768, BK=32.
// ---------------------------------------------------------------------------
__device__ __forceinline__ void gemm128_mainloop(
    const ushort_t* __restrict__ A, const ushort_t* __restrict__ Bt,
    int rowBase, int colBase, ushort_t* ldsA, ushort_t* ldsB, f32x4 acc[4][4]) {
  const int tid = threadIdx.x;
  const int wave = tid >> 6, lane = tid & 63;
  const int wr = wave >> 1, wc = wave & 1;
  const int lrow = lane & 15, lk = lane >> 4;
  const int sr = tid >> 2, sk = (tid & 3) * 8;
  const int K = C_DIM;

  const ushort_t* ga0 = A  + (size_t)(rowBase + sr)      * K + sk;
  const ushort_t* ga1 = A  + (size_t)(rowBase + 64 + sr) * K + sk;
  const ushort_t* gb0 = Bt + (size_t)(colBase + sr)      * K + sk;
  const ushort_t* gb1 = Bt + (size_t)(colBase + 64 + sr) * K + sk;
  ushort_t* la = ldsA + sr * 32 + sk;
  ushort_t* lb = ldsB + sr * 32 + sk;

  for (int kt = 0; kt < K; kt += 32) {
    gload_lds16(ga0 + kt, la);
    gload_lds16(ga1 + kt, la + 64 * 32);
    gload_lds16(gb0 + kt, lb);
    gload_lds16(gb1 + kt, lb + 64 * 32);
    asm volatile("s_waitcnt vmcnt(0)" ::: "memory");
    __syncthreads();
    bf16x8 af[4], bfr[4];
#pragma unroll
    for (int m = 0; m < 4; m++)
      af[m] = *(const bf16x8*)(ldsA + (wr * 64 + m * 16 + lrow) * 32 + lk * 8);
#pragma unroll
    for (int n = 0; n < 4; n++)
      bfr[n] = *(const bf16x8*)(ldsB + (wc * 64 + n * 16 + lrow) * 32 + lk * 8);
#pragma unroll
    for (int m = 0; m < 4; m++)
#pragma unroll
      for (int n = 0; n < 4; n++)
        acc[m][n] = __builtin_amdgcn_mfma_f32_16x16x32_bf16(af[m], bfr[n], acc[m][n], 0, 0, 0);
    __syncthreads();
  }
}

// ---------------------------------------------------------------------------
// 3) fused QKV projection.  grid = (6 colTiles, 32 rowTiles, 3 matrices)
// ---------------------------------------------------------------------------
__global__ __launch_bounds__(256) void gemm_qkv_kernel(
    const ushort_t* __restrict__ Xq, const ushort_t* __restrict__ Xk,
    const ushort_t* __restrict__ Xv,
    const ushort_t* __restrict__ Wqt, const ushort_t* __restrict__ Wkt,
    const ushort_t* __restrict__ Wvt,
    const float* __restrict__ bq, const float* __restrict__ bk,
    const float* __restrict__ bv,
    ushort_t* Qh, ushort_t* Kh, ushort_t* Vt) {
  const int mat = blockIdx.z;
  const ushort_t* A  = mat == 0 ? Xq  : mat == 1 ? Xk  : Xv;
  const ushort_t* Bt = mat == 0 ? Wqt : mat == 1 ? Wkt : Wvt;
  const float* bias  = mat == 0 ? bq  : mat == 1 ? bk  : bv;

  __shared__ __align__(16) ushort_t ldsA[128 * 32];
  __shared__ __align__(16) ushort_t ldsB[128 * 32];

  const int rowBase = blockIdx.y * 128;
  const int colBase = blockIdx.x * 128;
  f32x4 acc[4][4];
#pragma unroll
  for (int m = 0; m < 4; m++)
#pragma unroll
    for (int n = 0; n < 4; n++)
#pragma unroll
      for (int r = 0; r < 4; r++) acc[m][n][r] = 0.f;

  gemm128_mainloop(A, Bt, rowBase, colBase, ldsA, ldsB, acc);

  const int lane = threadIdx.x & 63, wave = threadIdx.x >> 6;
  const int wr = wave >> 1, wc = wave & 1;
  const int lrow = lane & 15, lk = lane >> 4;
  const float sc = (mat == 0) ? SCALE : 1.0f;

  __hip_bfloat16* dqk = (__hip_bfloat16*)(mat == 0 ? Qh : Kh);
  __hip_bfloat16* dvt = (__hip_bfloat16*)Vt;
#pragma unroll
  for (int n = 0; n < 4; n++) {
    const int col = colBase + wc * 64 + n * 16 + lrow;
    const float bval = bias[col];
    const int hh = col >> 6, dd = col & 63;
#pragma unroll
    for (int m = 0; m < 4; m++) {
#pragma unroll
      for (int r = 0; r < 4; r++) {
        const int row = rowBase + wr * 64 + m * 16 + lk * 4 + r;
        const int bb = row >> 11, nn = row & 2047;
        const float val = (acc[m][n][r] + bval) * sc;
        if (mat < 2) {
          dqk[(((size_t)(bb * HEADS + hh) * SEQ + nn) << 6) + dd] = __float2bfloat16(val);
        } else {
          dvt[((size_t)(bb * HEADS + hh) * DH + dd) * SEQ + nn] = __float2bfloat16(val);
        }
      }
    }
  }
}

// ---------------------------------------------------------------------------
// 4) flash attention, 32x32 MFMA swapped form + XCD swizzle + kv-split.
//    flat grid 768 = 8 XCD x {3 bh-groups x 16 qTiles x 2 kv-splits}.
//    Decode keeps all blocks of one bh on ONE XCD (K/V stay in its L2).
//    Each block: 4 waves x 32 q-rows, kv in [split*1024, +1024).
//    Writes UNNORMALIZED partial O^T (bf16) + per-row (m,l) for combine.
// ---------------------------------------------------------------------------
__global__ __launch_bounds__(256) void attn_kernel(
    const ushort_t* __restrict__ Qh, const ushort_t* __restrict__ Kh,
    const ushort_t* __restrict__ Vt, ushort_t* __restrict__ Opart,
    float2* __restrict__ Ml) {
  // XCD-aware decode (assumes RR dispatch: block fb -> XCD fb%8)
  const int fb   = blockIdx.x;
  const int xcd  = fb & 7;
  const int slot = fb >> 3;            // 0..95
  const int g    = slot >> 5;          // 0..2
  const int rem  = slot & 31;
  const int qt    = rem & 15;          // 0..15
  const int split = rem >> 4;          // 0..1
  const int bh    = xcd + 8 * g;       // 0..23

  const ushort_t* Qp = Qh + (size_t)bh * SEQ * DH;
  const ushort_t* Kp = Kh + (size_t)bh * SEQ * DH;
  const ushort_t* Vp = Vt + (size_t)bh * DH * SEQ;

  const int tid = threadIdx.x, wave = tid >> 6, lane = tid & 63;
  const int lq = lane & 31;           // q-row (and K/V row) index within tile
  const int hi = lane >> 5;           // lane half
  const int qrow0 = qt * 128 + wave * 32;
  const int kv0 = split * KVSPAN;

  // Q B-frags (pre-scaled by 1/8): qf[ks] = Q[qrow0+lq][ks*16 + hi*8 + j]
  bf16x8 qf[4];
#pragma unroll
  for (int ks = 0; ks < 4; ks++)
    qf[ks] = *(const bf16x8*)&Qp[(size_t)(qrow0 + lq) * DH + ks * 16 + hi * 8];

  // K A-frags, register double-buffer
  bf16x8 kfA[4], kfB[4];
#pragma unroll
  for (int ks = 0; ks < 4; ks++)
    kfA[ks] = *(const bf16x8*)&Kp[(size_t)(kv0 + lq) * DH + ks * 16 + hi * 8];

  f32x16 oacc[2];
#pragma unroll
  for (int dt = 0; dt < 2; dt++)
#pragma unroll
    for (int r = 0; r < 16; r++) oacc[dt][r] = 0.f;
  float mrun = -3e38f, lrun = 0.f;

#pragma unroll 1
  for (int it = 0; it < KVSPAN / 32; it++) {
    const int kv = kv0 + it * 32;
    const bf16x8* kc = (it & 1) ? kfB : kfA;
    bf16x8*       kn = (it & 1) ? kfA : kfB;

    // ---- S^T = K Q^T (32x32 tile, Dh=64 -> 4 chained mfma) ----
    f32x16 st;
#pragma unroll
    for (int r = 0; r < 16; r++) st[r] = 0.f;
    __builtin_amdgcn_s_setprio(1);
#pragma unroll
    for (int ks = 0; ks < 4; ks++)
      st = __builtin_amdgcn_mfma_f32_32x32x16_bf16(kc[ks], qf[ks], st, 0, 0, 0);
    __builtin_amdgcn_s_setprio(0);

    // ---- V frags for THIS tile (issued now, consumed after softmax) ----
    bf16x8 vf[2][2];
#pragma unroll
    for (int dt = 0; dt < 2; dt++)
#pragma unroll
      for (int s = 0; s < 2; s++)
        vf[dt][s] = *(const bf16x8*)&Vp[(size_t)(dt * 32 + lq) * SEQ + kv + s * 16 + hi * 8];

    // ---- prefetch next K tile (wraps within this split's range) ----
    const int nkv = kv0 + (((it + 1) & (KVSPAN / 32 - 1)) * 32);
#pragma unroll
    for (int ks = 0; ks < 4; ks++)
      kn[ks] = *(const bf16x8*)&Kp[(size_t)(nkv + lq) * DH + ks * 16 + hi * 8];

    // ---- online softmax: row q = lq, split across lane pair (l, l+32) ----
    float tm = st[0];
#pragma unroll
    for (int r = 1; r < 16; r++) tm = fmaxf(tm, st[r]);
    tm = xhalf_max(tm);
    float m = mrun;
    if (!__all(tm <= mrun + 8.f)) {           // defer-max (T13)
      m = fmaxf(mrun, tm);
      const float fac = __expf(mrun - m);
      mrun = m;
      lrun *= fac;
#pragma unroll
      for (int dt = 0; dt < 2; dt++)
#pragma unroll
        for (int r = 0; r < 16; r++) oacc[dt][r] *= fac;
    }
    float ps = 0.f;
#pragma unroll
    for (int r = 0; r < 16; r++) {
      float p = __expf(st[r] - m);
      st[r] = p;
      ps += p;
    }
    lrun += xhalf_sum(ps);

    // ---- P -> bf16 B-operand frags: 8 cvt_pk + 4 permlane32_swap (T12) ----
    unsigned pk[8];
#pragma unroll
    for (int i = 0; i < 8; i++) pk[i] = cvtpk(st[2 * i], st[2 * i + 1]);
    uint32x4 a0, a1;
    {
      i32x2 r02 = __builtin_amdgcn_permlane32_swap((int)pk[0], (int)pk[2], false, false);
      i32x2 r13 = __builtin_amdgcn_permlane32_swap((int)pk[1], (int)pk[3], false, false);
      a0.x = (unsigned)r02.x; a0.y = (unsigned)r13.x;
      a0.z = (unsigned)r02.y; a0.w = (unsigned)r13.y;
      i32x2 r46 = __builtin_amdgcn_permlane32_swap((int)pk[4], (int)pk[6], false, false);
      i32x2 r57 = __builtin_amdgcn_permlane32_swap((int)pk[5], (int)pk[7], false, false);
      a1.x = (unsigned)r46.x; a1.y = (unsigned)r57.x;
      a1.z = (unsigned)r46.y; a1.w = (unsigned)r57.y;
    }
    const bf16x8 w0 = __builtin_bit_cast(bf16x8, a0);
    const bf16x8 w1 = __builtin_bit_cast(bf16x8, a1);

    // ---- O^T += V^T P^T ----
    __builtin_amdgcn_s_setprio(1);
#pragma unroll
    for (int dt = 0; dt < 2; dt++) {
      oacc[dt] = __builtin_amdgcn_mfma_f32_32x32x16_bf16(vf[dt][0], w0, oacc[dt], 0, 0, 0);
      oacc[dt] = __builtin_amdgcn_mfma_f32_32x32x16_bf16(vf[dt][1], w1, oacc[dt], 0, 0, 0);
    }
    __builtin_amdgcn_s_setprio(0);
  }

  // ---- epilogue: UNNORMALIZED partial O^T -> Opart[split][rid][d], m/l ----
  const int rid = bh * SEQ + qrow0 + lq;
  ushort_t* Oprow = Opart + ((size_t)split * MROWS + rid) * DH;
#pragma unroll
  for (int dt = 0; dt < 2; dt++)
#pragma unroll
    for (int gg = 0; gg < 4; gg++) {
      ushort4 w;
      w.x = f2bf(oacc[dt][gg * 4 + 0]);
      w.y = f2bf(oacc[dt][gg * 4 + 1]);
      w.z = f2bf(oacc[dt][gg * 4 + 2]);
      w.w = f2bf(oacc[dt][gg * 4 + 3]);
      *(ushort4*)&Oprow[dt * 32 + gg * 8 + hi * 4] = w;
    }
  if (hi == 0) Ml[(size_t)split * MROWS + rid] = make_float2(mrun, lrun);
}

// ---------------------------------------------------------------------------
// 4b) combine the two kv-split partials -> Obf [MTOT, C] bf16
// ---------------------------------------------------------------------------
__global__ __launch_bounds__(256) void attn_combine_kernel(
    const ushort_t* __restrict__ Opart, const float2* __restrict__ Ml,
    ushort_t* __restrict__ O) {
  const int t = threadIdx.x;
  const int rid = blockIdx.x * 4 + (t >> 6);
  const int col = t & 63;
  const float2 ml0 = Ml[rid];
  const float2 ml1 = Ml[(size_t)MROWS + rid];
  const float M = fmaxf(ml0.x, ml1.x);
  const float w0 = __expf(ml0.x - M), w1 = __expf(ml1.x - M);
  const float inv = 1.f / (w0 * ml0.y + w1 * ml1.y);
  const float o0 = __bfloat162float(__builtin_bit_cast(__hip_bfloat16,
                     Opart[(size_t)rid * DH + col]));
  const float o1 = __bfloat162float(__builtin_bit_cast(__hip_bfloat16,
                     Opart[((size_t)MROWS + rid) * DH + col]));
  const float o = (w0 * o0 + w1 * o1) * inv;
  const int bh = rid >> 11, n = rid & 2047;
  const int b = bh / HEADS, h = bh - b * HEADS;
  ((__hip_bfloat16*)O)[(size_t)(b * SEQ + n) * C_DIM + h * DH + col] =
      __float2bfloat16(o);
}

// ---------------------------------------------------------------------------
// 5) output projection + bias + residual -> fp32 X
// ---------------------------------------------------------------------------
__global__ __launch_bounds__(256) void gemm_out_kernel(
    const ushort_t* __restrict__ Obf, const ushort_t* __restrict__ Wot,
    const float* __restrict__ bo, const float* __restrict__ query,
    float* __restrict__ X) {
  __shared__ __align__(16) ushort_t ldsA[128 * 32];
  __shared__ __align__(16) ushort_t ldsB[128 * 32];
  const int rowBase = blockIdx.y * 128;
  const int colBase = blockIdx.x * 128;
  f32x4 acc[4][4];
#pragma unroll
  for (int m = 0; m < 4; m++)
#pragma unroll
    for (int n = 0; n < 4; n++)
#pragma unroll
      for (int r = 0; r < 4; r++) acc[m][n][r] = 0.f;

  gemm128_mainloop(Obf, Wot, rowBase, colBase, ldsA, ldsB, acc);

  const int lane = threadIdx.x & 63, wave = threadIdx.x >> 6;
  const int wr = wave >> 1, wc = wave & 1;
  const int lrow = lane & 15, lk = lane >> 4;
#pragma unroll
  for (int n = 0; n < 4; n++) {
    const int col = colBase + wc * 64 + n * 16 + lrow;
    const float bval = bo[col];
#pragma unroll
    for (int m = 0; m < 4; m++) {
#pragma unroll
      for (int r = 0; r < 4; r++) {
        const int row = rowBase + wr * 64 + m * 16 + lk * 4 + r;
        const size_t idx = (size_t)row * C_DIM + col;
        X[idx] = acc[m][n][r] + bval + query[idx];
      }
    }
  }
}

// ---------------------------------------------------------------------------
// 6) LayerNorm over rows of X -> d_out (fp32)
// ---------------------------------------------------------------------------
__global__ __launch_bounds__(256) void ln_kernel(
    const float* __restrict__ X, const float* __restrict__ gamma,
    const float* __restrict__ beta, float* __restrict__ out) {
  const int row = blockIdx.x, tid = threadIdx.x;
  const float* xr = X + (size_t)row * C_DIM;
  float x0 = xr[tid], x1 = xr[tid + 256], x2 = xr[tid + 512];
  float s = x0 + x1 + x2;
  float sq = x0 * x0 + x1 * x1 + x2 * x2;
#pragma unroll
  for (int off = 32; off; off >>= 1) {
    s  += __shfl_xor(s, off);
    sq += __shfl_xor(sq, off);
  }
  __shared__ float as_[4], aq_[4];
  if ((tid & 63) == 0) { as_[tid >> 6] = s; aq_[tid >> 6] = sq; }
  __syncthreads();
  s  = as_[0] + as_[1] + as_[2] + as_[3];
  sq = aq_[0] + aq_[1] + aq_[2] + aq_[3];
  const float mean = s * (1.f / C_DIM);
  const float var  = sq * (1.f / C_DIM) - mean * mean;
  const float rstd = rsqrtf(var + EPS);
  float* orow = out + (size_t)row * C_DIM;
  orow[tid]       = (x0 - mean) * rstd * gamma[tid]       + beta[tid];
  orow[tid + 256] = (x1 - mean) * rstd * gamma[tid + 256] + beta[tid + 256];
  orow[tid + 512] = (x2 - mean) * rstd * gamma[tid + 512] + beta[tid + 512];
}

// ---------------------------------------------------------------------------
extern "C" void kernel_launch(void* const* d_in, const int* in_sizes, int n_in,
                              void* d_out, int out_size, void* d_ws, size_t ws_size,
                              hipStream_t stream) {
  (void)in_sizes; (void)n_in; (void)out_size; (void)ws_size;
  const float* query  = (const float*)d_in[0];
  const float* key_in = (const float*)d_in[1];
  const float* value  = (const float*)d_in[2];
  const float* Wq = (const float*)d_in[3];
  const float* bq = (const float*)d_in[4];
  const float* Wk = (const float*)d_in[5];
  const float* bk = (const float*)d_in[6];
  const float* Wv = (const float*)d_in[7];
  const float* bv = (const float*)d_in[8];
  const float* Wo = (const float*)d_in[9];
  const float* bo = (const float*)d_in[10];
  const float* gamma = (const float*)d_in[11];
  const float* beta  = (const float*)d_in[12];

  char* ws = (char*)d_ws;
  ushort_t* Xq  = (ushort_t*)(ws + B_XQ);
  ushort_t* Xk  = (ushort_t*)(ws + B_XK);
  ushort_t* Xv  = (ushort_t*)(ws + B_XV);
  ushort_t* Wqt = (ushort_t*)(ws + B_WQT);
  ushort_t* Wkt = (ushort_t*)(ws + B_WKT);
  ushort_t* Wvt = (ushort_t*)(ws + B_WVT);
  ushort_t* Wot = (ushort_t*)(ws + B_WOT);
  ushort_t* Qh  = (ushort_t*)(ws + B_QH);
  ushort_t* Kh  = (ushort_t*)(ws + B_KH);
  ushort_t* Vt  = (ushort_t*)(ws + B_VT);
  ushort_t* Obf = (ushort_t*)(ws + B_O);
  float*    Xr  = (float*)(ws + B_XR);
  ushort_t* Opart = (ushort_t*)(ws + B_OP);   // overlays Xq/Xk (dead by then)
  float2*   Ml    = (float2*)(ws + B_ML);
  float*    out = (float*)d_out;

  const int n4 = (int)(SZ_X / 4);
  cvt3_kernel<<<dim3(n4 / 256, 3), 256, 0, stream>>>(query, key_in, value,
                                                     Xq, Xk, Xv, n4);

  wtrans_kernel<<<dim3(24, 24, 4), 256, 0, stream>>>(Wq, Wk, Wv, Wo, Wqt, Wkt, Wvt, Wot);

  gemm_qkv_kernel<<<dim3(6, 32, 3), 256, 0, stream>>>(Xq, Xk, Xv, Wqt, Wkt, Wvt,
                                                      bq, bk, bv, Qh, Kh, Vt);

  attn_kernel<<<8 * 3 * 16 * NSPLIT, 256, 0, stream>>>(Qh, Kh, Vt, Opart, Ml);

  attn_combine_kernel<<<MROWS / 4, 256, 0, stream>>>(Opart, Ml, Obf);

  gemm_out_kernel<<<dim3(6, 32), 256, 0, stream>>>(Obf, Wot, bo, query, Xr);

  ln_kernel<<<MTOT, 256, 0, stream>>>(Xr, gamma, beta, out);
}

// Round 7
// 249.463 us; speedup vs baseline: 1.4403x; 1.1130x over previous
//
#include <hip/hip_runtime.h>
#include <hip/hip_bf16.h>

// ---------------------------------------------------------------------------
// CrossAttention block: softmax(QK^T/sqrt(d)) V, out-proj, residual, LayerNorm
// B=2, N=2048, C=768, H=12, Dh=64.  bf16 MFMA everywhere, fp32 accumulation.
// R7: Q/K/V stored FRAGMENT-MAJOR by the QKV epilogue so every attention
//     load is a contiguous 1KB wave load (was: 64-lane row-gather, ~32
//     cache lines per load -> memory-pipe bound at 512 lines/iter).
//     Attention math/structure unchanged from R6 (32x32 swapped MFMA,
//     permlane softmax, kv-split x2, XCD swizzle, setprio).
// ---------------------------------------------------------------------------

typedef unsigned short ushort_t;
typedef __bf16 bf16x8 __attribute__((ext_vector_type(8)));
typedef float  f32x4  __attribute__((ext_vector_type(4)));
typedef float  f32x16 __attribute__((ext_vector_type(16)));
typedef unsigned int uint32x4 __attribute__((ext_vector_type(4)));
typedef int    i32x2  __attribute__((ext_vector_type(2)));

constexpr int C_DIM  = 768;
constexpr int HEADS  = 12;
constexpr int DH     = 64;
constexpr int BATCH  = 2;
constexpr int SEQ    = 2048;
constexpr int MTOT   = BATCH * SEQ;          // 4096 rows of X
constexpr int MROWS  = BATCH * HEADS * SEQ;  // 49152 attention rows
constexpr int NSPLIT = 2;
constexpr int KVSPAN = SEQ / NSPLIT;         // 1024 kv per split
constexpr int HSZ    = SEQ * DH;             // 131072 elems per (b,h)
constexpr float EPS  = 1e-5f;
constexpr float SCALE = 0.125f;              // Dh^-0.5 (folded into Q proj)

// workspace layout (bytes)
constexpr size_t SZ_X = (size_t)MTOT * C_DIM;
constexpr size_t SZ_W = (size_t)C_DIM * C_DIM;
constexpr size_t B_XQ  = 0;
constexpr size_t B_XK  = B_XQ  + SZ_X * 2;
constexpr size_t B_XV  = B_XK  + SZ_X * 2;
constexpr size_t B_WQT = B_XV  + SZ_X * 2;
constexpr size_t B_WKT = B_WQT + SZ_W * 2;
constexpr size_t B_WVT = B_WKT + SZ_W * 2;
constexpr size_t B_WOT = B_WVT + SZ_W * 2;
constexpr size_t B_QH  = B_WOT + SZ_W * 2;      // QF frag-major bf16 (pre-scaled)
constexpr size_t B_KH  = B_QH  + SZ_X * 2;      // KF frag-major bf16
constexpr size_t B_VT  = B_KH  + SZ_X * 2;      // VF frag-major bf16
constexpr size_t B_O   = B_VT  + SZ_X * 2;      // [MTOT,C] bf16 attn output
constexpr size_t B_XR  = B_O   + SZ_X * 2;      // [MTOT,C] fp32 pre-LN
// attn partials OVERLAY the Xq/Xk/Xv region (dead after gemm_qkv):
constexpr size_t B_OP  = B_XQ;                              // [2][MROWS][64] bf16
constexpr size_t B_ML  = B_OP + (size_t)NSPLIT * MROWS * DH * 2;  // [2][MROWS] float2

__device__ __forceinline__ ushort_t f2bf(float f) {
  __hip_bfloat16 h = __float2bfloat16(f);
  return __builtin_bit_cast(unsigned short, h);
}

// hardware packed f32x2 -> bf16x2 convert (RNE), one VALU inst
__device__ __forceinline__ unsigned cvtpk(float lo, float hi) {
  unsigned r;
  asm("v_cvt_pk_bf16_f32 %0, %1, %2" : "=v"(r) : "v"(lo), "v"(hi));
  return r;
}
// cross-half (lane l <-> l+32) max / sum via permlane32_swap (VALU pipe)
__device__ __forceinline__ float xhalf_max(float x) {
  i32x2 r = __builtin_amdgcn_permlane32_swap(
      __builtin_bit_cast(int, x), __builtin_bit_cast(int, x), false, false);
  return fmaxf(__builtin_bit_cast(float, r.x), __builtin_bit_cast(float, r.y));
}
__device__ __forceinline__ float xhalf_sum(float x) {
  i32x2 r = __builtin_amdgcn_permlane32_swap(
      __builtin_bit_cast(int, x), __builtin_bit_cast(int, x), false, false);
  return __builtin_bit_cast(float, r.x) + __builtin_bit_cast(float, r.y);
}

// async global->LDS, 16B per lane.  LDS dest must be linear (base + lane*16).
__device__ __forceinline__ void gload_lds16(const void* g, void* l) {
  __builtin_amdgcn_global_load_lds(
      (const __attribute__((address_space(1))) unsigned int*)g,
      (__attribute__((address_space(3))) unsigned int*)l,
      16, 0, 0);
}

// ---------------------------------------------------------------------------
// 1) fp32 -> bf16 elementwise convert, all three activations in one launch
// ---------------------------------------------------------------------------
__global__ __launch_bounds__(256) void cvt3_kernel(
    const float* __restrict__ s0, const float* __restrict__ s1,
    const float* __restrict__ s2,
    ushort_t* __restrict__ d0, ushort_t* __restrict__ d1,
    ushort_t* __restrict__ d2, int n4) {
  const float* src = blockIdx.y == 0 ? s0 : blockIdx.y == 1 ? s1 : s2;
  ushort_t*    dst = blockIdx.y == 0 ? d0 : blockIdx.y == 1 ? d1 : d2;
  int i = blockIdx.x * 256 + threadIdx.x;
  if (i >= n4) return;
  float4 v = ((const float4*)src)[i];
  ushort4 o;
  o.x = f2bf(v.x); o.y = f2bf(v.y); o.z = f2bf(v.z); o.w = f2bf(v.w);
  ((ushort4*)dst)[i] = o;
}

// ---------------------------------------------------------------------------
// 2) transpose+convert the 4 weight matrices:  Wt[n][k] = W[k][n]  (bf16)
// ---------------------------------------------------------------------------
__global__ __launch_bounds__(256) void wtrans_kernel(
    const float* __restrict__ W0, const float* __restrict__ W1,
    const float* __restrict__ W2, const float* __restrict__ W3,
    ushort_t* T0, ushort_t* T1, ushort_t* T2, ushort_t* T3) {
  const float* W = blockIdx.z == 0 ? W0 : blockIdx.z == 1 ? W1 : blockIdx.z == 2 ? W2 : W3;
  ushort_t*    T = blockIdx.z == 0 ? T0 : blockIdx.z == 1 ? T1 : blockIdx.z == 2 ? T2 : T3;
  __shared__ float tile[32][33];
  int tx = threadIdx.x & 31, ty = threadIdx.x >> 5;   // 32 x 8
  int x0 = blockIdx.x * 32, y0 = blockIdx.y * 32;
#pragma unroll
  for (int i = 0; i < 32; i += 8)
    tile[ty + i][tx] = W[(size_t)(y0 + ty + i) * C_DIM + x0 + tx];
  __syncthreads();
#pragma unroll
  for (int i = 0; i < 32; i += 8)
    T[(size_t)(x0 + ty + i) * C_DIM + y0 + tx] = f2bf(tile[tx][ty + i]);
}

// ---------------------------------------------------------------------------
// GEMM mainloop: C[128x128] = A[128xK] * Bt[128xK]^T, K=768, BK=32.
// ---------------------------------------------------------------------------
__device__ __forceinline__ void gemm128_mainloop(
    const ushort_t* __restrict__ A, const ushort_t* __restrict__ Bt,
    int rowBase, int colBase, ushort_t* ldsA, ushort_t* ldsB, f32x4 acc[4][4]) {
  const int tid = threadIdx.x;
  const int wave = tid >> 6, lane = tid & 63;
  const int wr = wave >> 1, wc = wave & 1;
  const int lrow = lane & 15, lk = lane >> 4;
  const int sr = tid >> 2, sk = (tid & 3) * 8;
  const int K = C_DIM;

  const ushort_t* ga0 = A  + (size_t)(rowBase + sr)      * K + sk;
  const ushort_t* ga1 = A  + (size_t)(rowBase + 64 + sr) * K + sk;
  const ushort_t* gb0 = Bt + (size_t)(colBase + sr)      * K + sk;
  const ushort_t* gb1 = Bt + (size_t)(colBase + 64 + sr) * K + sk;
  ushort_t* la = ldsA + sr * 32 + sk;
  ushort_t* lb = ldsB + sr * 32 + sk;

  for (int kt = 0; kt < K; kt += 32) {
    gload_lds16(ga0 + kt, la);
    gload_lds16(ga1 + kt, la + 64 * 32);
    gload_lds16(gb0 + kt, lb);
    gload_lds16(gb1 + kt, lb + 64 * 32);
    asm volatile("s_waitcnt vmcnt(0)" ::: "memory");
    __syncthreads();
    bf16x8 af[4], bfr[4];
#pragma unroll
    for (int m = 0; m < 4; m++)
      af[m] = *(const bf16x8*)(ldsA + (wr * 64 + m * 16 + lrow) * 32 + lk * 8);
#pragma unroll
    for (int n = 0; n < 4; n++)
      bfr[n] = *(const bf16x8*)(ldsB + (wc * 64 + n * 16 + lrow) * 32 + lk * 8);
#pragma unroll
    for (int m = 0; m < 4; m++)
#pragma unroll
      for (int n = 0; n < 4; n++)
        acc[m][n] = __builtin_amdgcn_mfma_f32_16x16x32_bf16(af[m], bfr[n], acc[m][n], 0, 0, 0);
    __syncthreads();
  }
}

// ---------------------------------------------------------------------------
// 3) fused QKV projection.  grid = (6 colTiles, 32 rowTiles, 3 matrices)
//    Writes FRAGMENT-MAJOR layouts (element (bh, token nn, dim dd) -> the
//    exact lane/register the attention MFMA needs):
//      Q/K: [bh][t32][ks][lane][j]   lane = (nn&31) + 32*((dd>>3)&1)
//           t32 = nn>>5, ks = dd>>4, j = dd&7
//      V:   [bh][kvt][dt][s][lane][j] lane = (dd&31) + 32*((nn>>3)&1)
//           kvt = nn>>5, s = (nn>>4)&1, dt = dd>>5, j = nn&7
// ---------------------------------------------------------------------------
__global__ __launch_bounds__(256) void gemm_qkv_kernel(
    const ushort_t* __restrict__ Xq, const ushort_t* __restrict__ Xk,
    const ushort_t* __restrict__ Xv,
    const ushort_t* __restrict__ Wqt, const ushort_t* __restrict__ Wkt,
    const ushort_t* __restrict__ Wvt,
    const float* __restrict__ bq, const float* __restrict__ bk,
    const float* __restrict__ bv,
    ushort_t* QF, ushort_t* KF, ushort_t* VF) {
  const int mat = blockIdx.z;
  const ushort_t* A  = mat == 0 ? Xq  : mat == 1 ? Xk  : Xv;
  const ushort_t* Bt = mat == 0 ? Wqt : mat == 1 ? Wkt : Wvt;
  const float* bias  = mat == 0 ? bq  : mat == 1 ? bk  : bv;

  __shared__ __align__(16) ushort_t ldsA[128 * 32];
  __shared__ __align__(16) ushort_t ldsB[128 * 32];

  const int rowBase = blockIdx.y * 128;
  const int colBase = blockIdx.x * 128;
  f32x4 acc[4][4];
#pragma unroll
  for (int m = 0; m < 4; m++)
#pragma unroll
    for (int n = 0; n < 4; n++)
#pragma unroll
      for (int r = 0; r < 4; r++) acc[m][n][r] = 0.f;

  gemm128_mainloop(A, Bt, rowBase, colBase, ldsA, ldsB, acc);

  const int lane = threadIdx.x & 63, wave = threadIdx.x >> 6;
  const int wr = wave >> 1, wc = wave & 1;
  const int lrow = lane & 15, lk = lane >> 4;
  const float sc = (mat == 0) ? SCALE : 1.0f;

  __hip_bfloat16* dqk = (__hip_bfloat16*)(mat == 0 ? QF : KF);
  __hip_bfloat16* dvt = (__hip_bfloat16*)VF;
#pragma unroll
  for (int n = 0; n < 4; n++) {
    const int col = colBase + wc * 64 + n * 16 + lrow;
    const float bval = bias[col];
    const int hh = col >> 6, dd = col & 63;
#pragma unroll
    for (int m = 0; m < 4; m++) {
#pragma unroll
      for (int r = 0; r < 4; r++) {
        const int row = rowBase + wr * 64 + m * 16 + lk * 4 + r;
        const int bb = row >> 11, nn = row & 2047;
        const int bh = bb * HEADS + hh;
        const float val = (acc[m][n][r] + bval) * sc;
        if (mat < 2) {
          const int t32 = nn >> 5, r32 = nn & 31;
          const int ks = dd >> 4, hi2 = (dd >> 3) & 1, j = dd & 7;
          const size_t addr = (size_t)bh * HSZ + (size_t)(((t32 << 2) + ks) << 9)
                              + ((r32 + (hi2 << 5)) << 3) + j;
          dqk[addr] = __float2bfloat16(val);
        } else {
          const int kvt = nn >> 5, s = (nn >> 4) & 1, hi2 = (nn >> 3) & 1, j = nn & 7;
          const int dt = dd >> 5, r32 = dd & 31;
          const size_t addr = (size_t)bh * HSZ
                              + (size_t)((((kvt << 1) + dt) * 2 + s) << 9)
                              + ((r32 + (hi2 << 5)) << 3) + j;
          dvt[addr] = __float2bfloat16(val);
        }
      }
    }
  }
}

// ---------------------------------------------------------------------------
// 4) flash attention, 32x32 MFMA swapped form + XCD swizzle + kv-split.
//    All Q/K/V loads are contiguous 1KB wave loads from fragment-major
//    buffers: ptr = base + fragIdx*512 + lane*8.  Zero LDS.
// ---------------------------------------------------------------------------
__global__ __launch_bounds__(256) void attn_kernel(
    const ushort_t* __restrict__ QF, const ushort_t* __restrict__ KF,
    const ushort_t* __restrict__ VF, ushort_t* __restrict__ Opart,
    float2* __restrict__ Ml) {
  // XCD-aware decode (assumes RR dispatch: block fb -> XCD fb%8)
  const int fb   = blockIdx.x;
  const int xcd  = fb & 7;
  const int slot = fb >> 3;            // 0..95
  const int g    = slot >> 5;          // 0..2
  const int rem  = slot & 31;
  const int qt    = rem & 15;          // 0..15
  const int split = rem >> 4;          // 0..1
  const int bh    = xcd + 8 * g;       // 0..23

  const int tid = threadIdx.x, wave = tid >> 6, lane = tid & 63;
  const int lq = lane & 31;
  const int hi = lane >> 5;
  const int qrow0 = qt * 128 + wave * 32;
  const int qt32 = qrow0 >> 5;              // 0..63
  const int kvt0 = split * (KVSPAN / 32);   // base 32-kv tile

  const ushort_t* Qb = QF + (size_t)bh * HSZ + (lane << 3);
  const ushort_t* Kb = KF + (size_t)bh * HSZ + (lane << 3);
  const ushort_t* Vb = VF + (size_t)bh * HSZ + (lane << 3);

  // Q B-frags (pre-scaled by 1/8)
  bf16x8 qf[4];
#pragma unroll
  for (int ks = 0; ks < 4; ks++)
    qf[ks] = *(const bf16x8*)(Qb + (((qt32 << 2) + ks) << 9));

  // K A-frags, register double-buffer
  bf16x8 kfA[4], kfB[4];
#pragma unroll
  for (int ks = 0; ks < 4; ks++)
    kfA[ks] = *(const bf16x8*)(Kb + (((kvt0 << 2) + ks) << 9));

  f32x16 oacc[2];
#pragma unroll
  for (int dt = 0; dt < 2; dt++)
#pragma unroll
    for (int r = 0; r < 16; r++) oacc[dt][r] = 0.f;
  float mrun = -3e38f, lrun = 0.f;

#pragma unroll 1
  for (int it = 0; it < KVSPAN / 32; it++) {
    const int kvt = kvt0 + it;
    const bf16x8* kc = (it & 1) ? kfB : kfA;
    bf16x8*       kn = (it & 1) ? kfA : kfB;

    // ---- S^T = K Q^T (32x32 tile, Dh=64 -> 4 chained mfma) ----
    f32x16 st;
#pragma unroll
    for (int r = 0; r < 16; r++) st[r] = 0.f;
    __builtin_amdgcn_s_setprio(1);
#pragma unroll
    for (int ks = 0; ks < 4; ks++)
      st = __builtin_amdgcn_mfma_f32_32x32x16_bf16(kc[ks], qf[ks], st, 0, 0, 0);
    __builtin_amdgcn_s_setprio(0);

    // ---- V frags for THIS tile (issued now, consumed after softmax) ----
    bf16x8 vf[2][2];
#pragma unroll
    for (int dt = 0; dt < 2; dt++)
#pragma unroll
      for (int s = 0; s < 2; s++)
        vf[dt][s] = *(const bf16x8*)(Vb + (((((kvt << 1) + dt) << 1) + s) << 9));

    // ---- prefetch next K tile (wraps within this split's range) ----
    const int nkvt = kvt0 + ((it + 1) & (KVSPAN / 32 - 1));
#pragma unroll
    for (int ks = 0; ks < 4; ks++)
      kn[ks] = *(const bf16x8*)(Kb + (((nkvt << 2) + ks) << 9));

    // ---- online softmax: row q = lq, split across lane pair (l, l+32) ----
    float tm = st[0];
#pragma unroll
    for (int r = 1; r < 16; r++) tm = fmaxf(tm, st[r]);
    tm = xhalf_max(tm);
    float m = mrun;
    if (!__all(tm <= mrun + 8.f)) {           // defer-max (T13)
      m = fmaxf(mrun, tm);
      const float fac = __expf(mrun - m);
      mrun = m;
      lrun *= fac;
#pragma unroll
      for (int dt = 0; dt < 2; dt++)
#pragma unroll
        for (int r = 0; r < 16; r++) oacc[dt][r] *= fac;
    }
    float ps = 0.f;
#pragma unroll
    for (int r = 0; r < 16; r++) {
      float p = __expf(st[r] - m);
      st[r] = p;
      ps += p;
    }
    lrun += xhalf_sum(ps);

    // ---- P -> bf16 B-operand frags: 8 cvt_pk + 4 permlane32_swap (T12) ----
    unsigned pk[8];
#pragma unroll
    for (int i = 0; i < 8; i++) pk[i] = cvtpk(st[2 * i], st[2 * i + 1]);
    uint32x4 a0, a1;
    {
      i32x2 r02 = __builtin_amdgcn_permlane32_swap((int)pk[0], (int)pk[2], false, false);
      i32x2 r13 = __builtin_amdgcn_permlane32_swap((int)pk[1], (int)pk[3], false, false);
      a0.x = (unsigned)r02.x; a0.y = (unsigned)r13.x;
      a0.z = (unsigned)r02.y; a0.w = (unsigned)r13.y;
      i32x2 r46 = __builtin_amdgcn_permlane32_swap((int)pk[4], (int)pk[6], false, false);
      i32x2 r57 = __builtin_amdgcn_permlane32_swap((int)pk[5], (int)pk[7], false, false);
      a1.x = (unsigned)r46.x; a1.y = (unsigned)r57.x;
      a1.z = (unsigned)r46.y; a1.w = (unsigned)r57.y;
    }
    const bf16x8 w0 = __builtin_bit_cast(bf16x8, a0);
    const bf16x8 w1 = __builtin_bit_cast(bf16x8, a1);

    // ---- O^T += V^T P^T ----
    __builtin_amdgcn_s_setprio(1);
#pragma unroll
    for (int dt = 0; dt < 2; dt++) {
      oacc[dt] = __builtin_amdgcn_mfma_f32_32x32x16_bf16(vf[dt][0], w0, oacc[dt], 0, 0, 0);
      oacc[dt] = __builtin_amdgcn_mfma_f32_32x32x16_bf16(vf[dt][1], w1, oacc[dt], 0, 0, 0);
    }
    __builtin_amdgcn_s_setprio(0);
  }

  // ---- epilogue: UNNORMALIZED partial O^T -> Opart[split][rid][d], m/l ----
  const int rid = bh * SEQ + qrow0 + lq;
  ushort_t* Oprow = Opart + ((size_t)split * MROWS + rid) * DH;
#pragma unroll
  for (int dt = 0; dt < 2; dt++)
#pragma unroll
    for (int gg = 0; gg < 4; gg++) {
      ushort4 w;
      w.x = f2bf(oacc[dt][gg * 4 + 0]);
      w.y = f2bf(oacc[dt][gg * 4 + 1]);
      w.z = f2bf(oacc[dt][gg * 4 + 2]);
      w.w = f2bf(oacc[dt][gg * 4 + 3]);
      *(ushort4*)&Oprow[dt * 32 + gg * 8 + hi * 4] = w;
    }
  if (hi == 0) Ml[(size_t)split * MROWS + rid] = make_float2(mrun, lrun);
}

// ---------------------------------------------------------------------------
// 4b) combine the two kv-split partials -> Obf [MTOT, C] bf16
// ---------------------------------------------------------------------------
__global__ __launch_bounds__(256) void attn_combine_kernel(
    const ushort_t* __restrict__ Opart, const float2* __restrict__ Ml,
    ushort_t* __restrict__ O) {
  const int t = threadIdx.x;
  const int rid = blockIdx.x * 4 + (t >> 6);
  const int col = t & 63;
  const float2 ml0 = Ml[rid];
  const float2 ml1 = Ml[(size_t)MROWS + rid];
  const float M = fmaxf(ml0.x, ml1.x);
  const float w0 = __expf(ml0.x - M), w1 = __expf(ml1.x - M);
  const float inv = 1.f / (w0 * ml0.y + w1 * ml1.y);
  const float o0 = __bfloat162float(__builtin_bit_cast(__hip_bfloat16,
                     Opart[(size_t)rid * DH + col]));
  const float o1 = __bfloat162float(__builtin_bit_cast(__hip_bfloat16,
                     Opart[((size_t)MROWS + rid) * DH + col]));
  const float o = (w0 * o0 + w1 * o1) * inv;
  const int bh = rid >> 11, n = rid & 2047;
  const int b = bh / HEADS, h = bh - b * HEADS;
  ((__hip_bfloat16*)O)[(size_t)(b * SEQ + n) * C_DIM + h * DH + col] =
      __float2bfloat16(o);
}

// ---------------------------------------------------------------------------
// 5) output projection + bias + residual -> fp32 X
// ---------------------------------------------------------------------------
__global__ __launch_bounds__(256) void gemm_out_kernel(
    const ushort_t* __restrict__ Obf, const ushort_t* __restrict__ Wot,
    const float* __restrict__ bo, const float* __restrict__ query,
    float* __restrict__ X) {
  __shared__ __align__(16) ushort_t ldsA[128 * 32];
  __shared__ __align__(16) ushort_t ldsB[128 * 32];
  const int rowBase = blockIdx.y * 128;
  const int colBase = blockIdx.x * 128;
  f32x4 acc[4][4];
#pragma unroll
  for (int m = 0; m < 4; m++)
#pragma unroll
    for (int n = 0; n < 4; n++)
#pragma unroll
      for (int r = 0; r < 4; r++) acc[m][n][r] = 0.f;

  gemm128_mainloop(Obf, Wot, rowBase, colBase, ldsA, ldsB, acc);

  const int lane = threadIdx.x & 63, wave = threadIdx.x >> 6;
  const int wr = wave >> 1, wc = wave & 1;
  const int lrow = lane & 15, lk = lane >> 4;
#pragma unroll
  for (int n = 0; n < 4; n++) {
    const int col = colBase + wc * 64 + n * 16 + lrow;
    const float bval = bo[col];
#pragma unroll
    for (int m = 0; m < 4; m++) {
#pragma unroll
      for (int r = 0; r < 4; r++) {
        const int row = rowBase + wr * 64 + m * 16 + lk * 4 + r;
        const size_t idx = (size_t)row * C_DIM + col;
        X[idx] = acc[m][n][r] + bval + query[idx];
      }
    }
  }
}

// ---------------------------------------------------------------------------
// 6) LayerNorm over rows of X -> d_out (fp32)
// ---------------------------------------------------------------------------
__global__ __launch_bounds__(256) void ln_kernel(
    const float* __restrict__ X, const float* __restrict__ gamma,
    const float* __restrict__ beta, float* __restrict__ out) {
  const int row = blockIdx.x, tid = threadIdx.x;
  const float* xr = X + (size_t)row * C_DIM;
  float x0 = xr[tid], x1 = xr[tid + 256], x2 = xr[tid + 512];
  float s = x0 + x1 + x2;
  float sq = x0 * x0 + x1 * x1 + x2 * x2;
#pragma unroll
  for (int off = 32; off; off >>= 1) {
    s  += __shfl_xor(s, off);
    sq += __shfl_xor(sq, off);
  }
  __shared__ float as_[4], aq_[4];
  if ((tid & 63) == 0) { as_[tid >> 6] = s; aq_[tid >> 6] = sq; }
  __syncthreads();
  s  = as_[0] + as_[1] + as_[2] + as_[3];
  sq = aq_[0] + aq_[1] + aq_[2] + aq_[3];
  const float mean = s * (1.f / C_DIM);
  const float var  = sq * (1.f / C_DIM) - mean * mean;
  const float rstd = rsqrtf(var + EPS);
  float* orow = out + (size_t)row * C_DIM;
  orow[tid]       = (x0 - mean) * rstd * gamma[tid]       + beta[tid];
  orow[tid + 256] = (x1 - mean) * rstd * gamma[tid + 256] + beta[tid + 256];
  orow[tid + 512] = (x2 - mean) * rstd * gamma[tid + 512] + beta[tid + 512];
}

// ---------------------------------------------------------------------------
extern "C" void kernel_launch(void* const* d_in, const int* in_sizes, int n_in,
                              void* d_out, int out_size, void* d_ws, size_t ws_size,
                              hipStream_t stream) {
  (void)in_sizes; (void)n_in; (void)out_size; (void)ws_size;
  const float* query  = (const float*)d_in[0];
  const float* key_in = (const float*)d_in[1];
  const float* value  = (const float*)d_in[2];
  const float* Wq = (const float*)d_in[3];
  const float* bq = (const float*)d_in[4];
  const float* Wk = (const float*)d_in[5];
  const float* bk = (const float*)d_in[6];
  const float* Wv = (const float*)d_in[7];
  const float* bv = (const float*)d_in[8];
  const float* Wo = (const float*)d_in[9];
  const float* bo = (const float*)d_in[10];
  const float* gamma = (const float*)d_in[11];
  const float* beta  = (const float*)d_in[12];

  char* ws = (char*)d_ws;
  ushort_t* Xq  = (ushort_t*)(ws + B_XQ);
  ushort_t* Xk  = (ushort_t*)(ws + B_XK);
  ushort_t* Xv  = (ushort_t*)(ws + B_XV);
  ushort_t* Wqt = (ushort_t*)(ws + B_WQT);
  ushort_t* Wkt = (ushort_t*)(ws + B_WKT);
  ushort_t* Wvt = (ushort_t*)(ws + B_WVT);
  ushort_t* Wot = (ushort_t*)(ws + B_WOT);
  ushort_t* QF  = (ushort_t*)(ws + B_QH);
  ushort_t* KF  = (ushort_t*)(ws + B_KH);
  ushort_t* VF  = (ushort_t*)(ws + B_VT);
  ushort_t* Obf = (ushort_t*)(ws + B_O);
  float*    Xr  = (float*)(ws + B_XR);
  ushort_t* Opart = (ushort_t*)(ws + B_OP);   // overlays Xq/Xk (dead by then)
  float2*   Ml    = (float2*)(ws + B_ML);
  float*    out = (float*)d_out;

  const int n4 = (int)(SZ_X / 4);
  cvt3_kernel<<<dim3(n4 / 256, 3), 256, 0, stream>>>(query, key_in, value,
                                                     Xq, Xk, Xv, n4);

  wtrans_kernel<<<dim3(24, 24, 4), 256, 0, stream>>>(Wq, Wk, Wv, Wo, Wqt, Wkt, Wvt, Wot);

  gemm_qkv_kernel<<<dim3(6, 32, 3), 256, 0, stream>>>(Xq, Xk, Xv, Wqt, Wkt, Wvt,
                                                      bq, bk, bv, QF, KF, VF);

  attn_kernel<<<8 * 3 * 16 * NSPLIT, 256, 0, stream>>>(QF, KF, VF, Opart, Ml);

  attn_combine_kernel<<<MROWS / 4, 256, 0, stream>>>(Opart, Ml, Obf);

  gemm_out_kernel<<<dim3(6, 32), 256, 0, stream>>>(Obf, Wot, bo, query, Xr);

  ln_kernel<<<MTOT, 256, 0, stream>>>(Xr, gamma, beta, out);
}